// Round 1
// 1177.238 us; speedup vs baseline: 1.3105x; 1.3105x over previous
//
#include <hip/hip_runtime.h>
#include <math.h>

typedef float floatx4 __attribute__((ext_vector_type(4)));
typedef __bf16 bf16x8 __attribute__((ext_vector_type(8)));
typedef unsigned short u16;

#define LDK 72  // LDS row stride in ushorts (144B, 16B-aligned)

__device__ inline u16 to_bf16(float f) {
  union { float f; unsigned u; } v; v.f = f;
  unsigned u = v.u;
  u += 0x7FFFu + ((u >> 16) & 1u);
  return (u16)(u >> 16);
}
__device__ inline float bf2f(u16 h) {
  union { unsigned u; float f; } v; v.u = ((unsigned)h) << 16; return v.f;
}

struct GemmArgs {
  const void* A; const void* B; void* C;
  int lda, ldb, ldc, N, Kc;
  long sA1, sA2, sB1, sB2, sC1, sC2;
  float alpha;
  const float* bias;
  const float* res; int ldres;
  int amode;   // 0: A fp32, 1: A bf16
  int cmode;   // 0: fp32 C, 1: bf16 C, 2: bf16 C transposed, 3: fp32 atomicAdd
  int act;     // exact gelu
  int smode;   // shifted bf16 scatter: C[row][col+row-511] = bf16(v) if >=0
  int bdiv, kparts;
  int gx, gy;  // grid decomposition of this descriptor's block range
};

#define MAXG 6
struct GemmBatch {
  GemmArgs g[MAXG];
  int end[MAXG];   // cumulative block-count ends
  int ng;
};

// Grouped GEMM: one launch covers up to MAXG independent GEMMs. Each block
// selects its descriptor from its linear block id (raises waves/CU for the
// many 256-block projection GEMMs from 4 to 24+).
__global__ __launch_bounds__(256) void gemmb_k(GemmBatch gb) {
  int bid = blockIdx.x;
  int gi = 0;
  while (bid >= gb.end[gi]) ++gi;
  const GemmArgs g = gb.g[gi];
  int lb = bid - (gi ? gb.end[gi - 1] : 0);
  int bx = lb % g.gx;
  int rem = lb / g.gx;
  int by = rem % g.gy;
  int z = rem / g.gy;

  int kp = z % g.kparts;
  int zz = z / g.kparts;
  int zi = zz / g.bdiv, zj = zz % g.bdiv;
  long aoff = (long)zi * g.sA1 + (long)zj * g.sA2;
  long boff = (long)zi * g.sB1 + (long)zj * g.sB2;
  long coff = (long)zi * g.sC1 + (long)zj * g.sC2;
  const float* Af = (const float*)g.A + aoff;
  const u16* Ah = (const u16*)g.A + aoff;
  const u16* Bh = (const u16*)g.B + boff;

  int m0 = by * 64, n0 = bx * 64;
  __shared__ u16 As[64][LDK];
  __shared__ u16 Bs[64][LDK];
  int tid = threadIdx.x;
  int wave = tid >> 6, lane = tid & 63;
  int wr = (wave >> 1) * 32, wc = (wave & 1) * 32;
  int lr = lane & 15, qrow = lane >> 4;

  floatx4 acc[2][2];
#pragma unroll
  for (int i = 0; i < 2; ++i)
#pragma unroll
    for (int j = 0; j < 2; ++j)
#pragma unroll
      for (int r = 0; r < 4; ++r) acc[i][j][r] = 0.f;

  int r = tid >> 2, kc = (tid & 3) << 4;
  int kb0 = kp * g.Kc, kb1 = kb0 + g.Kc;
  for (int k0 = kb0; k0 < kb1; k0 += 64) {
    if (g.amode == 0) {
      const float* ap = Af + (long)(m0 + r) * g.lda + k0 + kc;
      float4 a0 = *(const float4*)ap, a1 = *(const float4*)(ap + 4);
      float4 a2 = *(const float4*)(ap + 8), a3 = *(const float4*)(ap + 12);
      union { u16 s[8]; uint4 v; } u0, u1;
      u0.s[0] = to_bf16(a0.x); u0.s[1] = to_bf16(a0.y); u0.s[2] = to_bf16(a0.z); u0.s[3] = to_bf16(a0.w);
      u0.s[4] = to_bf16(a1.x); u0.s[5] = to_bf16(a1.y); u0.s[6] = to_bf16(a1.z); u0.s[7] = to_bf16(a1.w);
      u1.s[0] = to_bf16(a2.x); u1.s[1] = to_bf16(a2.y); u1.s[2] = to_bf16(a2.z); u1.s[3] = to_bf16(a2.w);
      u1.s[4] = to_bf16(a3.x); u1.s[5] = to_bf16(a3.y); u1.s[6] = to_bf16(a3.z); u1.s[7] = to_bf16(a3.w);
      *(uint4*)&As[r][kc] = u0.v; *(uint4*)&As[r][kc + 8] = u1.v;
    } else {
      const u16* ap = Ah + (long)(m0 + r) * g.lda + k0 + kc;
      *(uint4*)&As[r][kc] = *(const uint4*)ap;
      *(uint4*)&As[r][kc + 8] = *(const uint4*)(ap + 8);
    }
    {
      const u16* bp = Bh + (long)(n0 + r) * g.ldb + k0 + kc;
      *(uint4*)&Bs[r][kc] = *(const uint4*)bp;
      *(uint4*)&Bs[r][kc + 8] = *(const uint4*)(bp + 8);
    }
    __syncthreads();
#pragma unroll
    for (int ks = 0; ks < 2; ++ks) {
      int kq = ks * 32 + qrow * 8;
      bf16x8 a0 = *(const bf16x8*)&As[wr + lr][kq];
      bf16x8 a1 = *(const bf16x8*)&As[wr + 16 + lr][kq];
      bf16x8 b0 = *(const bf16x8*)&Bs[wc + lr][kq];
      bf16x8 b1 = *(const bf16x8*)&Bs[wc + 16 + lr][kq];
      acc[0][0] = __builtin_amdgcn_mfma_f32_16x16x32_bf16(a0, b0, acc[0][0], 0, 0, 0);
      acc[0][1] = __builtin_amdgcn_mfma_f32_16x16x32_bf16(a0, b1, acc[0][1], 0, 0, 0);
      acc[1][0] = __builtin_amdgcn_mfma_f32_16x16x32_bf16(a1, b0, acc[1][0], 0, 0, 0);
      acc[1][1] = __builtin_amdgcn_mfma_f32_16x16x32_bf16(a1, b1, acc[1][1], 0, 0, 0);
    }
    __syncthreads();
  }

#pragma unroll
  for (int mt = 0; mt < 2; ++mt)
#pragma unroll
    for (int nt = 0; nt < 2; ++nt) {
      int row0 = m0 + wr + mt * 16 + qrow * 4;
      int col = n0 + wc + nt * 16 + lr;
      if (g.cmode == 2) {
        ushort4 o;
        o.x = to_bf16(acc[mt][nt][0] * g.alpha);
        o.y = to_bf16(acc[mt][nt][1] * g.alpha);
        o.z = to_bf16(acc[mt][nt][2] * g.alpha);
        o.w = to_bf16(acc[mt][nt][3] * g.alpha);
        *(ushort4*)((u16*)g.C + coff + (long)col * g.ldc + row0) = o;
      } else {
#pragma unroll
        for (int rr = 0; rr < 4; ++rr) {
          int row = row0 + rr;
          float v = acc[mt][nt][rr] * g.alpha;
          if (g.cmode == 3) {
            atomicAdd((float*)g.C + coff + (long)row * g.ldc + col, v);
          } else if (g.smode) {
            int oc = col + row - 511;
            if (oc >= 0) ((u16*)g.C + coff)[(long)row * g.ldc + oc] = to_bf16(v);
          } else {
            if (g.bias) v += g.bias[col];
            if (g.res) v += g.res[(long)row * g.ldres + col];
            if (g.act) v = 0.5f * v * (1.0f + erff(v * 0.70710678118654752f));
            if (g.cmode == 1) ((u16*)g.C + coff)[(long)row * g.ldc + col] = to_bf16(v);
            else ((float*)g.C + coff)[(long)row * g.ldc + col] = v;
          }
        }
      }
    }
}

struct FAttnArgs {
  const u16* Q; const u16* K; const u16* V; const u16* QP;  // QP = pre-shifted SQP
  void* O; float* Opart; float* ml;
  int L, nsplit; long sKb, sVb; int ldV;
  float scale; int obf16;
};

struct FBatch {
  FAttnArgs a[3];
  int zend[3];  // cumulative z ends
  int nf;
};

// Fused flash attention, double-buffered K/V, optional pre-shifted pos bias,
// optional KV-split (unnormalized partials + m/l for a combine pass).
// Batched over the z-axis: up to 3 independent attention problems per launch.
__global__ __launch_bounds__(256) void fattnb_k(FBatch fb) {
  int zg = blockIdx.z;
  int fi = 0;
  while (zg >= fb.zend[fi]) ++fi;
  const FAttnArgs a = fb.a[fi];
  int zl = zg - (fi ? fb.zend[fi - 1] : 0);

  int qt = blockIdx.x, h = blockIdx.y;
  int b = zl / a.nsplit, sp = zl % a.nsplit;
  int Lc = a.L / a.nsplit, kt0 = sp * Lc, T = Lc >> 6;
  int tid = threadIdx.x, wave = tid >> 6, lane = tid & 63;
  int lr = lane & 15, quad = lane >> 4;
  __shared__ u16 Qs[64][LDK];
  __shared__ u16 Ks[2][64][LDK];
  __shared__ u16 Vs[2][64][LDK];
  __shared__ u16 Qp[4][16][LDK];
  __shared__ u16 Ps[4][16][LDK];
  int r = tid >> 2, c = (tid & 3) << 4;
  {
    const u16* qp = a.Q + (long)(b * 512 + qt * 64 + r) * 512 + h * 64 + c;
    *(uint4*)&Qs[r][c] = *(const uint4*)qp;
    *(uint4*)&Qs[r][c + 8] = *(const uint4*)(qp + 8);
  }
  const u16* Kb = a.K + (long)b * a.sKb + h * 64;
  const u16* Vb = a.V + (long)b * a.sVb + (long)(h * 64) * a.ldV;
  int qrow16 = lane >> 2, qc = (lane & 3) << 4;  // wave-private SQP tile loader
  const u16* QPr = a.QP ? a.QP + ((long)b * 8 + h) * 589824 +
                          (long)(qt * 64 + wave * 16 + qrow16) * 1152 : nullptr;
  // preload tile 0 straight into LDS buffer 0
  {
    const u16* kp = Kb + (long)(kt0 + r) * 512 + c;
    *(uint4*)&Ks[0][r][c] = *(const uint4*)kp;
    *(uint4*)&Ks[0][r][c + 8] = *(const uint4*)(kp + 8);
    const u16* vp = Vb + (long)r * a.ldV + kt0 + c;
    *(uint4*)&Vs[0][r][c] = *(const uint4*)vp;
    *(uint4*)&Vs[0][r][c + 8] = *(const uint4*)(vp + 8);
  }
  uint4 qpr0, qpr1;
  if (QPr) {  // 16 u16 per lane: two uint4s
    qpr0 = *(const uint4*)(QPr + kt0 + qc);
    qpr1 = *(const uint4*)(QPr + kt0 + qc + 8);
  }

  float m_run[4], l_run[4];
  floatx4 oacc[4];
#pragma unroll
  for (int i = 0; i < 4; ++i) {
    m_run[i] = -1e30f; l_run[i] = 0.f;
#pragma unroll
    for (int j = 0; j < 4; ++j) oacc[i][j] = 0.f;
  }

  for (int t = 0; t < T; ++t) {
    int cur = t & 1;
    bool more = (t + 1) < T;
    __syncthreads();
    // issue next-tile global loads AFTER the barrier (s_barrier drains vmcnt);
    // they overlap the whole compute phase below, waited at the LDS store.
    uint4 pk0, pk1, pv0, pv1;
    if (more) {
      int kt = kt0 + (t + 1) * 64;
      const u16* kp = Kb + (long)(kt + r) * 512 + c;
      pk0 = *(const uint4*)kp; pk1 = *(const uint4*)(kp + 8);
      const u16* vp = Vb + (long)r * a.ldV + kt + c;
      pv0 = *(const uint4*)vp; pv1 = *(const uint4*)(vp + 8);
    }
    floatx4 sacc[4];
#pragma unroll
    for (int nt = 0; nt < 4; ++nt)
#pragma unroll
      for (int j = 0; j < 4; ++j) sacc[nt][j] = 0.f;
#pragma unroll
    for (int ks = 0; ks < 2; ++ks) {
      int kq = ks * 32 + quad * 8;
      bf16x8 av = *(const bf16x8*)&Qs[wave * 16 + lr][kq];
#pragma unroll
      for (int nt = 0; nt < 4; ++nt) {
        bf16x8 bb = *(const bf16x8*)&Ks[cur][nt * 16 + lr][kq];
        sacc[nt] = __builtin_amdgcn_mfma_f32_16x16x32_bf16(av, bb, sacc[nt], 0, 0, 0);
      }
    }
    if (QPr) {
      // wave-private: store this tile's SQP regs, read per-element; no barrier needed
      *(uint4*)&Qp[wave][qrow16][qc] = qpr0;
      *(uint4*)&Qp[wave][qrow16][qc + 8] = qpr1;
#pragma unroll
      for (int nt = 0; nt < 4; ++nt)
#pragma unroll
        for (int rr = 0; rr < 4; ++rr)
          sacc[nt][rr] = sacc[nt][rr] * a.scale + bf2f(Qp[wave][quad * 4 + rr][nt * 16 + lr]);
      if (more) {
        qpr0 = *(const uint4*)(QPr + kt0 + (t + 1) * 64 + qc);
        qpr1 = *(const uint4*)(QPr + kt0 + (t + 1) * 64 + qc + 8);
      }
    } else {
#pragma unroll
      for (int nt = 0; nt < 4; ++nt)
#pragma unroll
        for (int rr = 0; rr < 4; ++rr) sacc[nt][rr] *= a.scale;
    }
    // online softmax (rows replicated across the 16 lanes of a quad)
#pragma unroll
    for (int rr = 0; rr < 4; ++rr) {
      float m = -1e30f;
#pragma unroll
      for (int nt = 0; nt < 4; ++nt) m = fmaxf(m, sacc[nt][rr]);
      for (int o = 8; o > 0; o >>= 1) m = fmaxf(m, __shfl_xor(m, o, 64));
      float mn = fmaxf(m_run[rr], m);
      float al = __expf(m_run[rr] - mn);
      m_run[rr] = mn;
      float s = 0.f;
#pragma unroll
      for (int nt = 0; nt < 4; ++nt) {
        float p = __expf(sacc[nt][rr] - mn);
        sacc[nt][rr] = p;
        s += p;
      }
      for (int o = 8; o > 0; o >>= 1) s += __shfl_xor(s, o, 64);
      l_run[rr] = l_run[rr] * al + s;
#pragma unroll
      for (int nt = 0; nt < 4; ++nt) oacc[nt][rr] *= al;
    }
    // P (C-layout) -> LDS -> A-layout (wave-private)
#pragma unroll
    for (int nt = 0; nt < 4; ++nt) {
      Ps[wave][quad * 4 + 0][nt * 16 + lr] = to_bf16(sacc[nt][0]);
      Ps[wave][quad * 4 + 1][nt * 16 + lr] = to_bf16(sacc[nt][1]);
      Ps[wave][quad * 4 + 2][nt * 16 + lr] = to_bf16(sacc[nt][2]);
      Ps[wave][quad * 4 + 3][nt * 16 + lr] = to_bf16(sacc[nt][3]);
    }
#pragma unroll
    for (int ks = 0; ks < 2; ++ks) {
      int kq = ks * 32 + quad * 8;
      bf16x8 av = *(const bf16x8*)&Ps[wave][lr][kq];
#pragma unroll
      for (int nt = 0; nt < 4; ++nt) {
        bf16x8 bb = *(const bf16x8*)&Vs[cur][nt * 16 + lr][kq];
        oacc[nt] = __builtin_amdgcn_mfma_f32_16x16x32_bf16(av, bb, oacc[nt], 0, 0, 0);
      }
    }
    if (more) {  // stage prefetched tile into the other buffer
      *(uint4*)&Ks[cur ^ 1][r][c] = pk0; *(uint4*)&Ks[cur ^ 1][r][c + 8] = pk1;
      *(uint4*)&Vs[cur ^ 1][r][c] = pv0; *(uint4*)&Vs[cur ^ 1][r][c + 8] = pv1;
    }
  }
  if (a.nsplit == 1) {
    float inv[4];
#pragma unroll
    for (int rr = 0; rr < 4; ++rr) inv[rr] = 1.f / l_run[rr];
#pragma unroll
    for (int nt = 0; nt < 4; ++nt)
#pragma unroll
      for (int rr = 0; rr < 4; ++rr) {
        long row = b * 512 + qt * 64 + wave * 16 + quad * 4 + rr;
        float v = oacc[nt][rr] * inv[rr];
        if (a.obf16) ((u16*)a.O)[row * 512 + h * 64 + nt * 16 + lr] = to_bf16(v);
        else ((float*)a.O)[row * 512 + h * 64 + nt * 16 + lr] = v;
      }
  } else {
#pragma unroll
    for (int nt = 0; nt < 4; ++nt)
#pragma unroll
      for (int rr = 0; rr < 4; ++rr) {
        long row = b * 512 + qt * 64 + wave * 16 + quad * 4 + rr;
        a.Opart[((long)sp * 2048 + row) * 512 + h * 64 + nt * 16 + lr] = oacc[nt][rr];
      }
    if (lr == 0)
#pragma unroll
      for (int rr = 0; rr < 4; ++rr) {
        long row = b * 512 + qt * 64 + wave * 16 + quad * 4 + rr;
        long mi = (((long)sp * 2048 + row) * 8 + h) * 2;
        a.ml[mi] = m_run[rr]; a.ml[mi + 1] = l_run[rr];
      }
  }
}

__global__ __launch_bounds__(256) void fcomb_k(const float* __restrict__ Opart,
                                               const float* __restrict__ ml,
                                               void* __restrict__ O, int nsplit, int obf16) {
  long i = (long)blockIdx.x * 256 + threadIdx.x;
  int row = (int)(i >> 9), col = (int)(i & 511), h = col >> 6;
  float m = -1e30f;
  for (int s = 0; s < nsplit; ++s)
    m = fmaxf(m, ml[(((long)s * 2048 + row) * 8 + h) * 2]);
  float l = 0.f, o = 0.f;
  for (int s = 0; s < nsplit; ++s) {
    long mi = (((long)s * 2048 + row) * 8 + h) * 2;
    float w = __expf(ml[mi] - m);
    l += w * ml[mi + 1];
    o += w * Opart[(long)s * 1048576 + i];
  }
  float v = o / l;
  if (obf16) ((u16*)O)[i] = to_bf16(v);
  else ((float*)O)[i] = v;
}

__global__ __launch_bounds__(256) void embed_k(const int* __restrict__ trg,
                                               const float* __restrict__ embed,
                                               float* __restrict__ x) {
  int i = blockIdx.x * 256 + threadIdx.x;
  int row = i >> 9, d = i & 511;
  x[i] = embed[(long)trg[row] * 512 + d];
}

__global__ __launch_bounds__(256) void concat_kv_k(const float* __restrict__ cmem,
                                                   const float* __restrict__ mem,
                                                   const float* __restrict__ x,
                                                   u16* __restrict__ kv) {
  long i = (long)blockIdx.x * 256 + threadIdx.x;
  int d = i & 511;
  long t = (i >> 9) % 1152;
  long b = (i >> 9) / 1152;
  float v;
  if (t < 128) v = cmem[(b * 128 + t) * 512 + d];
  else if (t < 640) v = mem[(b * 512 + (t - 128)) * 512 + d];
  else v = x[(b * 512 + (t - 640)) * 512 + d];
  kv[i] = to_bf16(v);
}

__global__ __launch_bounds__(256) void layernorm_k(const float* __restrict__ X,
                                                   const float* __restrict__ g,
                                                   const float* __restrict__ b,
                                                   u16* __restrict__ Y) {
  long row = blockIdx.x;
  const float* x = X + row * 512;
  int tid = threadIdx.x;
  float v0 = x[tid], v1 = x[tid + 256];
  __shared__ float red[256];
  red[tid] = v0 + v1; __syncthreads();
  for (int o = 128; o > 0; o >>= 1) { if (tid < o) red[tid] += red[tid + o]; __syncthreads(); }
  float mu = red[0] * (1.f / 512.f);
  __syncthreads();
  float d0 = v0 - mu, d1 = v1 - mu;
  red[tid] = d0 * d0 + d1 * d1; __syncthreads();
  for (int o = 128; o > 0; o >>= 1) { if (tid < o) red[tid] += red[tid + o]; __syncthreads(); }
  float rstd = rsqrtf(red[0] * (1.f / 512.f) + 1e-5f);
  Y[row * 512 + tid] = to_bf16(d0 * rstd * g[tid] + b[tid]);
  Y[row * 512 + tid + 256] = to_bf16(d1 * rstd * g[tid + 256] + b[tid + 256]);
}

__global__ __launch_bounds__(256) void preset_k(float* __restrict__ C,
                                                const float* __restrict__ res,
                                                const float* __restrict__ bias, int nmask) {
  long i = (long)blockIdx.x * 256 + threadIdx.x;
  float v = 0.f;
  if (res) v += res[i];
  if (bias) v += bias[i & nmask];
  C[i] = v;
}

__global__ __launch_bounds__(256) void loss_k(const float* __restrict__ a,
                                              const float* __restrict__ b,
                                              float* __restrict__ acc) {
  float s = 0.f;
  for (long i = (long)blockIdx.x * 256 + threadIdx.x; i < 1048576; i += 256L * 128) {
    float d = a[i] - b[i]; s += d * d;
  }
  for (int o = 32; o > 0; o >>= 1) s += __shfl_xor(s, o, 64);
  __shared__ float red[4];
  if ((threadIdx.x & 63) == 0) red[threadIdx.x >> 6] = s;
  __syncthreads();
  if (threadIdx.x == 0) atomicAdd(acc, red[0] + red[1] + red[2] + red[3]);
}

__global__ __launch_bounds__(256) void transpose_bf16_k(const float* __restrict__ in,
                                                        u16* __restrict__ out, int K, int N) {
  long z = blockIdx.z;
  in += z * (long)K * N; out += z * (long)K * N;
  __shared__ float t[32][33];
  int n0 = blockIdx.x * 32, k0 = blockIdx.y * 32;
  int tx = threadIdx.x, ty = threadIdx.y;
  for (int j = 0; j < 32; j += 8) t[ty + j][tx] = in[(long)(k0 + ty + j) * N + n0 + tx];
  __syncthreads();
  for (int j = 0; j < 32; j += 8) out[(long)(n0 + ty + j) * K + k0 + tx] = to_bf16(t[tx][ty + j]);
}

__global__ __launch_bounds__(256) void convw_k(const float* __restrict__ in,
                                               u16* __restrict__ out) {
  int i = blockIdx.x * 256 + threadIdx.x;
  long z = blockIdx.z;
  int o = i >> 11, k = i & 2047;
  int r = k >> 9, d = k & 511;
  out[z * 1048576 + i] = to_bf16(in[z * 1048576 + o * 2048 + d * 4 + r]);
}

__global__ __launch_bounds__(256) void cvt_bf16_k(const float* __restrict__ in,
                                                  u16* __restrict__ out, int n) {
  int i = blockIdx.x * 256 + threadIdx.x;
  if (i < n) out[i] = to_bf16(in[i]);
}

__global__ __launch_bounds__(256) void finalize_k(const float* __restrict__ x,
                                                  const float* __restrict__ loss,
                                                  float* __restrict__ out) {
  long i = (long)blockIdx.x * 256 + threadIdx.x;
  if (i < 1048576) out[i] = x[i];
  else if (i == 1048576) out[i] = loss[0] * (1.f / (1048576.f * 4.f));
}

extern "C" void kernel_launch(void* const* d_in, const int* in_sizes, int n_in,
                              void* d_out, int out_size, void* d_ws, size_t ws_size,
                              hipStream_t stream) {
  (void)in_sizes; (void)n_in; (void)out_size;
  const int* trg = (const int*)d_in[0];
  const float* latent = (const float*)d_in[3];
  const float* mems = (const float*)d_in[4];
  const float* cmems = (const float*)d_in[5];
  const float* pos_emb = (const float*)d_in[6];
  const float* embed = (const float*)d_in[7];
  const float* W_self = (const float*)d_in[8];
  const float* ln1_g = (const float*)d_in[9];
  const float* ln1_b = (const float*)d_in[10];
  const float* conv_w = (const float*)d_in[11];
  const float* conv_b = (const float*)d_in[12];
  const float* W_src = (const float*)d_in[13];
  const float* ln2_g = (const float*)d_in[14];
  const float* ln2_b = (const float*)d_in[15];
  const float* w1 = (const float*)d_in[16];
  const float* b1 = (const float*)d_in[17];
  const float* w2 = (const float*)d_in[18];
  const float* b2 = (const float*)d_in[19];

  float* ws = (float*)d_ws;
  long off = 0;
  auto alloc = [&](long n) { float* p = ws + off; off += (n + 63) & ~63L; return p; };
  float* x    = alloc(1048576);
  float* t0   = alloc(1048576);
  float* t1   = alloc(1048576);
  float* ncm  = alloc(262144);
  float* ocm  = alloc(1048576);
  float* oold = alloc(1048576);
  float* Opart= alloc(2097152);       // aliases h1 (disjoint liveness: attn vs FF)
  u16* h1   = (u16*)Opart;            // [2048][2048] bf16
  float* mlb  = alloc(65536);         // [2][2048][8][2]
  float* Opart2 = alloc(2097152);     // cross-attn partials (co-runs with oold now)
  float* mlb2 = alloc(65536);
  // [2048][512] bf16 buffers need 1048576 u16 = 524288 floats each
  // (R6/R7 FAILED with alloc(262144): qb/xa/t1h overlapped -> in-place gemm races)
  u16* acat = (u16*)alloc(524288);
  u16* qb   = (u16*)alloc(524288);
  u16* qc   = (u16*)alloc(524288);    // cross-attn Q (co-lives with rattn Q now)
  u16* xa   = (u16*)alloc(524288);
  u16* t1h  = (u16*)alloc(524288);
  u16* kvcat= (u16*)alloc(1179648);
  u16* kbuf = (u16*)alloc(1179648);
  u16* vbuf = (u16*)alloc(1179648);
  u16* kmem = (u16*)alloc(524288);    // rattn target K proj (was reusing kbuf)
  u16* vmem = (u16*)alloc(524288);    // rattn target V proj (transposed, ldc=2048)
  u16* kcm  = (u16*)alloc(131072);
  u16* vcm  = (u16*)alloc(131072);
  u16* klat = (u16*)alloc(262144);
  u16* vlat = (u16*)alloc(262144);
  u16* SQP  = (u16*)alloc(9437184);   // [4][8][512][1152] bf16 pre-shifted, *8 folded
  u16* wts  = (u16*)alloc(2097152);
  u16* wsr  = (u16*)alloc(2097152);
  u16* w1t  = (u16*)alloc(2097152);
  u16* w2t  = (u16*)alloc(2097152);
  u16* cwt  = (u16*)alloc(2097152);
  u16* post = (u16*)alloc(294912);
  float* lossacc = alloc(64);
  if ((size_t)off * 4 > ws_size) return;

  hipMemsetAsync(lossacc, 0, 4, stream);
  hipMemsetAsync(SQP, 0, 37748736, stream);  // tail region (k>=641+q) is never scattered
  embed_k<<<4096, 256, 0, stream>>>(trg, embed, x);
  transpose_bf16_k<<<dim3(16, 16, 16), dim3(32, 8), 0, stream>>>(W_self, wts, 512, 512);
  transpose_bf16_k<<<dim3(16, 16, 16), dim3(32, 8), 0, stream>>>(W_src, wsr, 512, 512);
  transpose_bf16_k<<<dim3(64, 16, 4), dim3(32, 8), 0, stream>>>(w1, w1t, 512, 2048);
  transpose_bf16_k<<<dim3(16, 64, 4), dim3(32, 8), 0, stream>>>(w2, w2t, 2048, 512);
  convw_k<<<dim3(4096, 1, 4), 256, 0, stream>>>(conv_w, cwt);
  cvt_bf16_k<<<2304, 256, 0, stream>>>(pos_emb, post, 589824);

  auto ga = []() { GemmArgs g; g.alpha = 1.f; g.bias = nullptr; g.res = nullptr; g.ldres = 512;
                   g.amode = 0; g.cmode = 0; g.act = 0; g.smode = 0; g.bdiv = 1; g.kparts = 1;
                   g.sA1 = g.sA2 = g.sB1 = g.sB2 = g.sC1 = g.sC2 = 0; g.N = 0;
                   g.gx = g.gy = 1; return g; };
  // grouped-gemm batcher: accumulate up to MAXG descriptors, launch as one grid
  GemmBatch GB; GB.ng = 0; int gtot = 0;
  auto badd = [&](GemmArgs g, int gx, int gy, int gz) {
    g.gx = gx; g.gy = gy;
    GB.g[GB.ng] = g; gtot += gx * gy * gz; GB.end[GB.ng] = gtot; GB.ng++;
  };
  auto brun = [&]() {
    gemmb_k<<<dim3(gtot), 256, 0, stream>>>(GB);
    GB.ng = 0; gtot = 0;
  };
  auto run1 = [&](GemmArgs g, int gx, int gy, int gz) { badd(g, gx, gy, gz); brun(); };

  // batched flash-attention launcher (independent problems share one launch)
  FBatch FB; FB.nf = 0; int ztot = 0;
  auto fadd = [&](const u16* Q, const u16* K, const u16* V, const u16* QP, void* O,
                  int L, int nsplit, long sKb, long sVb, int ldV, int obf16,
                  float* Op, float* ml) {
    FAttnArgs a; a.Q = Q; a.K = K; a.V = V; a.QP = QP; a.O = O;
    a.Opart = Op; a.ml = ml;
    a.L = L; a.nsplit = nsplit; a.sKb = sKb; a.sVb = sVb; a.ldV = ldV;
    a.scale = 0.125f; a.obf16 = obf16;
    FB.a[FB.nf] = a; ztot += 4 * nsplit; FB.zend[FB.nf] = ztot; FB.nf++;
  };
  auto frun = [&]() {
    fattnb_k<<<dim3(8, 8, ztot), 256, 0, stream>>>(FB);
    FB.nf = 0; ztot = 0;
  };

  for (int l = 0; l < 4; ++l) {
    const u16* Wt0 = wts + (l * 4 + 0) * 262144;
    const u16* Wt1 = wts + (l * 4 + 1) * 262144;
    const u16* Wt2 = wts + (l * 4 + 2) * 262144;
    const u16* Wt3 = wts + (l * 4 + 3) * 262144;
    const u16* Ws0 = wsr + (l * 4 + 0) * 262144;
    const u16* Ws1 = wsr + (l * 4 + 1) * 262144;
    const u16* Ws2 = wsr + (l * 4 + 2) * 262144;
    const u16* Ws3 = wsr + (l * 4 + 3) * 262144;
    const float* mem_l = mems + (long)l * 1048576;
    const float* cmem_l = cmems + (long)l * 262144;

    // ===== prep: everything that depends only on layer inputs (x, mem, latent) =====
    concat_kv_k<<<9216, 256, 0, stream>>>(cmem_l, mem_l, x, kvcat);
    preset_k<<<1024, 256, 0, stream>>>(ncm, nullptr, conv_b + l * 512, 511);
    // batchP: {qb, conv->ncm, kmem, vmem, klat, vlat} = 1536 blocks, one launch
    { GemmArgs g = ga(); g.A = x; g.lda = 512; g.B = Wt0; g.ldb = 512; g.C = qb; g.ldc = 512;
      g.cmode = 1; g.Kc = 512; badd(g, 8, 32, 1); }
    { GemmArgs g = ga(); g.A = mem_l; g.lda = 2048; g.B = cwt + (long)l * 1048576; g.ldb = 2048;
      g.C = ncm; g.ldc = 512; g.cmode = 3; g.kparts = 8; g.Kc = 256; badd(g, 8, 8, 8); }
    { GemmArgs g = ga(); g.A = mem_l; g.lda = 512; g.B = Wt1; g.ldb = 512;
      g.C = kmem; g.ldc = 512; g.cmode = 1; g.Kc = 512; badd(g, 8, 32, 1); }
    { GemmArgs g = ga(); g.A = mem_l; g.lda = 512; g.B = Wt2; g.ldb = 512;
      g.C = vmem; g.ldc = 2048; g.cmode = 2; g.Kc = 512; badd(g, 8, 32, 1); }
    { GemmArgs g = ga(); g.A = latent; g.lda = 512; g.B = Ws1; g.ldb = 512;
      g.C = klat; g.ldc = 512; g.cmode = 1; g.Kc = 512; badd(g, 8, 16, 1); }
    { GemmArgs g = ga(); g.A = latent; g.lda = 512; g.B = Ws2; g.ldb = 512;
      g.C = vlat; g.ldc = 1024; g.cmode = 2; g.Kc = 512; badd(g, 8, 16, 1); }
    brun();

    // batch1: {kbuf, vbuf, kcm, vcm, SQP-scatter} = 5888 blocks, one launch
    { GemmArgs g = ga(); g.A = kvcat; g.amode = 1; g.lda = 512; g.B = Wt1; g.ldb = 512;
      g.C = kbuf; g.ldc = 512; g.cmode = 1; g.Kc = 512; badd(g, 8, 72, 1); }
    { GemmArgs g = ga(); g.A = kvcat; g.amode = 1; g.lda = 512; g.sA1 = 589824; g.B = Wt2; g.ldb = 512;
      g.C = vbuf; g.ldc = 1152; g.sC1 = 589824; g.cmode = 2; g.Kc = 512; badd(g, 8, 18, 4); }
    { GemmArgs g = ga(); g.A = ncm; g.lda = 512; g.B = Wt1; g.ldb = 512;
      g.C = kcm; g.ldc = 512; g.cmode = 1; g.Kc = 512; badd(g, 8, 8, 1); }
    { GemmArgs g = ga(); g.A = ncm; g.lda = 512; g.B = Wt2; g.ldb = 512;
      g.C = vcm; g.ldc = 512; g.cmode = 2; g.Kc = 512; badd(g, 8, 8, 1); }
    // SQP[b][h][q][k] = 8*(q . pos[h][k+511-q]) via shifted scatter epilogue, bf16
    { GemmArgs g = ga(); g.A = qb; g.amode = 1; g.lda = 512; g.sA1 = 262144; g.sA2 = 64;
      g.B = post; g.ldb = 64; g.sB1 = 0; g.sB2 = 73728;
      g.C = SQP; g.ldc = 1152; g.sC1 = 4718592; g.sC2 = 589824;
      g.smode = 1; g.alpha = 8.f; g.bdiv = 8; g.Kc = 64; badd(g, 18, 8, 32); }
    brun();

    // ===== self-attention =====
    fadd(qb, kbuf, vbuf, SQP, acat, 1152, 2, 589824, 589824, 1152, 1, Opart, mlb);
    frun();
    fcomb_k<<<4096, 256, 0, stream>>>(Opart, mlb, acat, 2, 1);
    { GemmArgs g = ga(); g.A = acat; g.amode = 1; g.lda = 512; g.B = Wt3; g.ldb = 512;
      g.C = t1; g.ldc = 512; g.res = x; g.Kc = 512; run1(g, 8, 32, 1); }
    layernorm_k<<<2048, 256, 0, stream>>>(t1, ln1_g + l * 512, ln1_b + l * 512, xa);

    // batchQ: {rattn Q, cross Q} (both from xa) = 512 blocks
    { GemmArgs g = ga(); g.A = xa; g.amode = 1; g.lda = 512; g.B = Wt0; g.ldb = 512;
      g.C = qb; g.ldc = 512; g.cmode = 1; g.Kc = 512; badd(g, 8, 32, 1); }
    { GemmArgs g = ga(); g.A = xa; g.amode = 1; g.lda = 512; g.B = Ws0; g.ldb = 512;
      g.C = qc; g.ldc = 512; g.cmode = 1; g.Kc = 512; badd(g, 8, 32, 1); }
    brun();

    // ===== rattn (compression loss) + cross attention, one batched launch =====
    fadd(qb, kcm, vcm, nullptr, ocm, 128, 1, 65536, 128, 512, 0, Opart, mlb);
    fadd(qb, kmem, vmem, nullptr, oold, 512, 2, 262144, 512, 2048, 0, Opart, mlb);
    fadd(qc, klat, vlat, nullptr, acat, 256, 2, 131072, 256, 1024, 1, Opart2, mlb2);
    frun();
    fcomb_k<<<4096, 256, 0, stream>>>(Opart, mlb, oold, 2, 0);
    fcomb_k<<<4096, 256, 0, stream>>>(Opart2, mlb2, acat, 2, 1);
    loss_k<<<128, 256, 0, stream>>>(ocm, oold, lossacc);

    { GemmArgs g = ga(); g.A = acat; g.amode = 1; g.lda = 512; g.B = Ws3; g.ldb = 512;
      g.C = t0; g.ldc = 512; g.Kc = 512; run1(g, 8, 32, 1); }
    layernorm_k<<<2048, 256, 0, stream>>>(t0, ln2_g + l * 512, ln2_b + l * 512, t1h);

    // ===== FF =====
    { GemmArgs g = ga(); g.A = t1h; g.amode = 1; g.lda = 512; g.B = w1t + (long)l * 1048576; g.ldb = 512;
      g.C = h1; g.ldc = 2048; g.cmode = 1; g.bias = b1 + l * 2048; g.act = 1; g.Kc = 512;
      run1(g, 32, 32, 1); }
    preset_k<<<4096, 256, 0, stream>>>(x, t0, b2 + l * 512, 511);
    { GemmArgs g = ga(); g.A = h1; g.amode = 1; g.lda = 2048; g.B = w2t + (long)l * 1048576; g.ldb = 2048;
      g.C = x; g.ldc = 512; g.cmode = 3; g.kparts = 4; g.Kc = 512; run1(g, 8, 32, 4); }
  }
  finalize_k<<<4097, 256, 0, stream>>>(x, lossacc, (float*)d_out);
}

// Round 2
// 1160.752 us; speedup vs baseline: 1.3291x; 1.0142x over previous
//
#include <hip/hip_runtime.h>
#include <math.h>

typedef float floatx4 __attribute__((ext_vector_type(4)));
typedef __bf16 bf16x8 __attribute__((ext_vector_type(8)));
typedef unsigned short u16;

#define LDK 72  // LDS row stride in ushorts for fattn (144B, 16B-aligned)

__device__ inline u16 to_bf16(float f) {
  union { float f; unsigned u; } v; v.f = f;
  unsigned u = v.u;
  u += 0x7FFFu + ((u >> 16) & 1u);
  return (u16)(u >> 16);
}
__device__ inline float bf2f(u16 h) {
  union { unsigned u; float f; } v; v.u = ((unsigned)h) << 16; return v.f;
}

// async global->LDS, 16B per lane. LDS dest must be wave-uniform base
// (HW adds lane*16). Swizzled LDS content achieved by pre-swizzling the
// per-lane GLOBAL source address (rule #21: both-sides-or-neither).
__device__ inline void gload16(const void* g, void* l) {
  __builtin_amdgcn_global_load_lds(
      (const __attribute__((address_space(1))) unsigned int*)g,
      (__attribute__((address_space(3))) unsigned int*)l, 16, 0, 0);
}

struct GemmArgs {
  const void* A; const void* B; void* C;
  int lda, ldb, ldc, N, Kc;
  long sA1, sA2, sB1, sB2, sC1, sC2;
  float alpha;
  const float* bias;
  const float* res; int ldres;
  const float* aml;  // amode=2: ml buffer [2][2048][8][2]
  int amode;   // 0: A fp32, 1: A bf16, 2: A = flash-split combine (Opart x2 + ml)
  int cmode;   // 0: fp32 C, 1: bf16 C, 2: bf16 C transposed, 3: fp32 atomicAdd
  int act;     // exact gelu
  int smode;   // shifted bf16 scatter: C[row][col+row-511] = bf16(v) if >=0
  int bdiv, kparts;
  int gx, gy;  // grid decomposition of this descriptor's block range
};

#define MAXG 6
struct GemmBatch {
  GemmArgs g[MAXG];
  int end[MAXG];   // cumulative block-count ends
  int ng;
};

// Grouped GEMM, 64x64 tile, K-step 64. Staging:
//  - bf16 A (amode=1) and B: global_load_lds dwordx4, LDS linear in lane,
//    XOR-swizzled content via pre-swizzled global source.
//  - fp32 A (amode=0) / combine A (amode=2): reg-stage + swizzled ds_write.
// Reads use the same swizzle: byte = (row<<7) + (col2B ^ ((row&7)<<4)).
__global__ __launch_bounds__(256) void gemmb_k(GemmBatch gb) {
  int bid = blockIdx.x;
  int gi = 0;
  while (bid >= gb.end[gi]) ++gi;
  const GemmArgs g = gb.g[gi];
  int lb = bid - (gi ? gb.end[gi - 1] : 0);
  int bx = lb % g.gx;
  int rem = lb / g.gx;
  int by = rem % g.gy;
  int z = rem / g.gy;

  int kp = z % g.kparts;
  int zz = z / g.kparts;
  int zi = zz / g.bdiv, zj = zz % g.bdiv;
  long aoff = (long)zi * g.sA1 + (long)zj * g.sA2;
  long boff = (long)zi * g.sB1 + (long)zj * g.sB2;
  long coff = (long)zi * g.sC1 + (long)zj * g.sC2;
  const float* Af = (const float*)g.A + aoff;
  const u16* Ah = (const u16*)g.A + aoff;
  const u16* Bh = (const u16*)g.B + boff;

  int m0 = by * 64, n0 = bx * 64;
  __shared__ u16 As[64][64];
  __shared__ u16 Bs[64][64];
  char* Asb = (char*)&As[0][0];
  char* Bsb = (char*)&Bs[0][0];
  int tid = threadIdx.x;
  int wave = tid >> 6, lane = tid & 63;
  int wr = (wave >> 1) * 32, wc = (wave & 1) * 32;
  int lr = lane & 15, qrow = lane >> 4;

  // async-staging geometry: lane covers LDS bytes o (linear); its global
  // source is the logical element whose swizzle lands at o.
  unsigned o0 = wave * 1024u + lane * 16u;
  unsigned o1 = o0 + 4096u;
  int ga_r0 = o0 >> 7, ga_r1 = o1 >> 7;
  int ga_c0 = (int)(o0 & 127u) ^ ((ga_r0 & 7) << 4);
  int ga_c1 = (int)(o1 & 127u) ^ ((ga_r1 & 7) << 4);
  long ldaB = (long)g.lda * 2, ldbB = (long)g.ldb * 2;
  // reg-staging geometry
  int r = tid >> 2, c16 = (tid & 3) << 4;
  int sw0 = (r << 7) + (((tid & 3) << 5) ^ ((r & 7) << 4));
  int sw1 = (r << 7) + ((((tid & 3) << 5) + 16) ^ ((r & 7) << 4));

  floatx4 acc[2][2];
#pragma unroll
  for (int i = 0; i < 2; ++i)
#pragma unroll
    for (int j = 0; j < 2; ++j)
#pragma unroll
      for (int rr = 0; rr < 4; ++rr) acc[i][j][rr] = 0.f;

  int kb0 = kp * g.Kc, kb1 = kb0 + g.Kc;
  for (int k0 = kb0; k0 < kb1; k0 += 64) {
    if (g.amode == 1) {
      const char* Ab = (const char*)Ah + ((long)m0 * g.lda + k0) * 2;
      gload16(Ab + ga_r0 * ldaB + ga_c0, Asb + wave * 1024);
      gload16(Ab + ga_r1 * ldaB + ga_c1, Asb + 4096 + wave * 1024);
    } else if (g.amode == 0) {
      const float* ap = Af + (long)(m0 + r) * g.lda + k0 + c16;
      float4 a0 = *(const float4*)ap, a1 = *(const float4*)(ap + 4);
      float4 a2 = *(const float4*)(ap + 8), a3 = *(const float4*)(ap + 12);
      union { u16 s[8]; uint4 v; } u0, u1;
      u0.s[0] = to_bf16(a0.x); u0.s[1] = to_bf16(a0.y); u0.s[2] = to_bf16(a0.z); u0.s[3] = to_bf16(a0.w);
      u0.s[4] = to_bf16(a1.x); u0.s[5] = to_bf16(a1.y); u0.s[6] = to_bf16(a1.z); u0.s[7] = to_bf16(a1.w);
      u1.s[0] = to_bf16(a2.x); u1.s[1] = to_bf16(a2.y); u1.s[2] = to_bf16(a2.z); u1.s[3] = to_bf16(a2.w);
      u1.s[4] = to_bf16(a3.x); u1.s[5] = to_bf16(a3.y); u1.s[6] = to_bf16(a3.z); u1.s[7] = to_bf16(a3.w);
      *(uint4*)(Asb + sw0) = u0.v; *(uint4*)(Asb + sw1) = u1.v;
    } else {  // amode 2: A = combine of 2 flash splits (ex-fcomb, fused)
      int row = m0 + r;
      int k = k0 + c16;               // all 16 cols in one head (k0%64==0)
      const float* mlp = g.aml + ((long)row * 8 + (k >> 6)) * 2;
      float m0v = mlp[0], l0v = mlp[1];
      float m1v = mlp[32768], l1v = mlp[32769];
      float mm = fmaxf(m0v, m1v);
      float w0 = __expf(m0v - mm), w1 = __expf(m1v - mm);
      float inv = 1.f / (w0 * l0v + w1 * l1v);
      w0 *= inv; w1 *= inv;
      const float* p0 = (const float*)g.A + (long)row * g.lda + k;
      const float* p1 = p0 + g.sA1;   // sA1 = split stride (floats)
      float4 x0 = *(const float4*)p0, x1 = *(const float4*)(p0 + 4);
      float4 x2 = *(const float4*)(p0 + 8), x3 = *(const float4*)(p0 + 12);
      float4 y0 = *(const float4*)p1, y1 = *(const float4*)(p1 + 4);
      float4 y2 = *(const float4*)(p1 + 8), y3 = *(const float4*)(p1 + 12);
      union { u16 s[8]; uint4 v; } u0, u1;
      u0.s[0] = to_bf16(w0 * x0.x + w1 * y0.x); u0.s[1] = to_bf16(w0 * x0.y + w1 * y0.y);
      u0.s[2] = to_bf16(w0 * x0.z + w1 * y0.z); u0.s[3] = to_bf16(w0 * x0.w + w1 * y0.w);
      u0.s[4] = to_bf16(w0 * x1.x + w1 * y1.x); u0.s[5] = to_bf16(w0 * x1.y + w1 * y1.y);
      u0.s[6] = to_bf16(w0 * x1.z + w1 * y1.z); u0.s[7] = to_bf16(w0 * x1.w + w1 * y1.w);
      u1.s[0] = to_bf16(w0 * x2.x + w1 * y2.x); u1.s[1] = to_bf16(w0 * x2.y + w1 * y2.y);
      u1.s[2] = to_bf16(w0 * x2.z + w1 * y2.z); u1.s[3] = to_bf16(w0 * x2.w + w1 * y2.w);
      u1.s[4] = to_bf16(w0 * x3.x + w1 * y3.x); u1.s[5] = to_bf16(w0 * x3.y + w1 * y3.y);
      u1.s[6] = to_bf16(w0 * x3.z + w1 * y3.z); u1.s[7] = to_bf16(w0 * x3.w + w1 * y3.w);
      *(uint4*)(Asb + sw0) = u0.v; *(uint4*)(Asb + sw1) = u1.v;
    }
    {
      const char* Bb = (const char*)Bh + ((long)n0 * g.ldb + k0) * 2;
      gload16(Bb + ga_r0 * ldbB + ga_c0, Bsb + wave * 1024);
      gload16(Bb + ga_r1 * ldbB + ga_c1, Bsb + 4096 + wave * 1024);
    }
    __syncthreads();   // drains vmcnt (gload) + lgkm (ds_write)
#pragma unroll
    for (int ks = 0; ks < 2; ++ks) {
      int xk = ((ks * 32 + qrow * 8) << 1) ^ ((lr & 7) << 4);
      int rA0 = wr + lr, rB0 = wc + lr;
      bf16x8 a0 = *(const bf16x8*)(Asb + (rA0 << 7) + xk);
      bf16x8 a1 = *(const bf16x8*)(Asb + ((rA0 + 16) << 7) + xk);
      bf16x8 b0 = *(const bf16x8*)(Bsb + (rB0 << 7) + xk);
      bf16x8 b1 = *(const bf16x8*)(Bsb + ((rB0 + 16) << 7) + xk);
      acc[0][0] = __builtin_amdgcn_mfma_f32_16x16x32_bf16(a0, b0, acc[0][0], 0, 0, 0);
      acc[0][1] = __builtin_amdgcn_mfma_f32_16x16x32_bf16(a0, b1, acc[0][1], 0, 0, 0);
      acc[1][0] = __builtin_amdgcn_mfma_f32_16x16x32_bf16(a1, b0, acc[1][0], 0, 0, 0);
      acc[1][1] = __builtin_amdgcn_mfma_f32_16x16x32_bf16(a1, b1, acc[1][1], 0, 0, 0);
    }
    __syncthreads();
  }

#pragma unroll
  for (int mt = 0; mt < 2; ++mt)
#pragma unroll
    for (int nt = 0; nt < 2; ++nt) {
      int row0 = m0 + wr + mt * 16 + qrow * 4;
      int col = n0 + wc + nt * 16 + lr;
      if (g.cmode == 2) {
        ushort4 o;
        o.x = to_bf16(acc[mt][nt][0] * g.alpha);
        o.y = to_bf16(acc[mt][nt][1] * g.alpha);
        o.z = to_bf16(acc[mt][nt][2] * g.alpha);
        o.w = to_bf16(acc[mt][nt][3] * g.alpha);
        *(ushort4*)((u16*)g.C + coff + (long)col * g.ldc + row0) = o;
      } else {
#pragma unroll
        for (int rr = 0; rr < 4; ++rr) {
          int row = row0 + rr;
          float v = acc[mt][nt][rr] * g.alpha;
          if (g.cmode == 3) {
            atomicAdd((float*)g.C + coff + (long)row * g.ldc + col, v);
          } else if (g.smode) {
            int oc = col + row - 511;
            if (oc >= 0) ((u16*)g.C + coff)[(long)row * g.ldc + oc] = to_bf16(v);
          } else {
            if (g.bias) v += g.bias[col];
            if (g.res) v += g.res[(long)row * g.ldres + col];
            if (g.act) v = 0.5f * v * (1.0f + erff(v * 0.70710678118654752f));
            if (g.cmode == 1) ((u16*)g.C + coff)[(long)row * g.ldc + col] = to_bf16(v);
            else ((float*)g.C + coff)[(long)row * g.ldc + col] = v;
          }
        }
      }
    }
}

struct FAttnArgs {
  const u16* Q; const u16* K; const u16* V; const u16* QP;  // QP = pre-shifted SQP
  void* O; float* Opart; float* ml;
  int L, nsplit; long sKb, sVb; int ldV;
  float scale; int obf16;
};

struct FBatch {
  FAttnArgs a[3];
  int zend[3];  // cumulative z ends
  int nf;
};

// Fused flash attention, double-buffered K/V, optional pre-shifted pos bias,
// optional KV-split (unnormalized partials + m/l; combine fused in consumers).
// Batched over the z-axis: up to 3 independent attention problems per launch.
__global__ __launch_bounds__(256) void fattnb_k(FBatch fb) {
  int zg = blockIdx.z;
  int fi = 0;
  while (zg >= fb.zend[fi]) ++fi;
  const FAttnArgs a = fb.a[fi];
  int zl = zg - (fi ? fb.zend[fi - 1] : 0);

  int qt = blockIdx.x, h = blockIdx.y;
  int b = zl / a.nsplit, sp = zl % a.nsplit;
  int Lc = a.L / a.nsplit, kt0 = sp * Lc, T = Lc >> 6;
  int tid = threadIdx.x, wave = tid >> 6, lane = tid & 63;
  int lr = lane & 15, quad = lane >> 4;
  __shared__ u16 Qs[64][LDK];
  __shared__ u16 Ks[2][64][LDK];
  __shared__ u16 Vs[2][64][LDK];
  __shared__ u16 Qp[4][16][LDK];
  __shared__ u16 Ps[4][16][LDK];
  int r = tid >> 2, c = (tid & 3) << 4;
  {
    const u16* qp = a.Q + (long)(b * 512 + qt * 64 + r) * 512 + h * 64 + c;
    *(uint4*)&Qs[r][c] = *(const uint4*)qp;
    *(uint4*)&Qs[r][c + 8] = *(const uint4*)(qp + 8);
  }
  const u16* Kb = a.K + (long)b * a.sKb + h * 64;
  const u16* Vb = a.V + (long)b * a.sVb + (long)(h * 64) * a.ldV;
  int qrow16 = lane >> 2, qc = (lane & 3) << 4;  // wave-private SQP tile loader
  const u16* QPr = a.QP ? a.QP + ((long)b * 8 + h) * 589824 +
                          (long)(qt * 64 + wave * 16 + qrow16) * 1152 : nullptr;
  // preload tile 0 straight into LDS buffer 0
  {
    const u16* kp = Kb + (long)(kt0 + r) * 512 + c;
    *(uint4*)&Ks[0][r][c] = *(const uint4*)kp;
    *(uint4*)&Ks[0][r][c + 8] = *(const uint4*)(kp + 8);
    const u16* vp = Vb + (long)r * a.ldV + kt0 + c;
    *(uint4*)&Vs[0][r][c] = *(const uint4*)vp;
    *(uint4*)&Vs[0][r][c + 8] = *(const uint4*)(vp + 8);
  }
  uint4 qpr0, qpr1;
  if (QPr) {  // 16 u16 per lane: two uint4s
    qpr0 = *(const uint4*)(QPr + kt0 + qc);
    qpr1 = *(const uint4*)(QPr + kt0 + qc + 8);
  }

  float m_run[4], l_run[4];
  floatx4 oacc[4];
#pragma unroll
  for (int i = 0; i < 4; ++i) {
    m_run[i] = -1e30f; l_run[i] = 0.f;
#pragma unroll
    for (int j = 0; j < 4; ++j) oacc[i][j] = 0.f;
  }

  for (int t = 0; t < T; ++t) {
    int cur = t & 1;
    bool more = (t + 1) < T;
    __syncthreads();
    // issue next-tile global loads AFTER the barrier (s_barrier drains vmcnt);
    // they overlap the whole compute phase below, waited at the LDS store.
    uint4 pk0, pk1, pv0, pv1;
    if (more) {
      int kt = kt0 + (t + 1) * 64;
      const u16* kp = Kb + (long)(kt + r) * 512 + c;
      pk0 = *(const uint4*)kp; pk1 = *(const uint4*)(kp + 8);
      const u16* vp = Vb + (long)r * a.ldV + kt + c;
      pv0 = *(const uint4*)vp; pv1 = *(const uint4*)(vp + 8);
    }
    floatx4 sacc[4];
#pragma unroll
    for (int nt = 0; nt < 4; ++nt)
#pragma unroll
      for (int j = 0; j < 4; ++j) sacc[nt][j] = 0.f;
#pragma unroll
    for (int ks = 0; ks < 2; ++ks) {
      int kq = ks * 32 + quad * 8;
      bf16x8 av = *(const bf16x8*)&Qs[wave * 16 + lr][kq];
#pragma unroll
      for (int nt = 0; nt < 4; ++nt) {
        bf16x8 bb = *(const bf16x8*)&Ks[cur][nt * 16 + lr][kq];
        sacc[nt] = __builtin_amdgcn_mfma_f32_16x16x32_bf16(av, bb, sacc[nt], 0, 0, 0);
      }
    }
    if (QPr) {
      // wave-private: store this tile's SQP regs, read per-element; no barrier needed
      *(uint4*)&Qp[wave][qrow16][qc] = qpr0;
      *(uint4*)&Qp[wave][qrow16][qc + 8] = qpr1;
#pragma unroll
      for (int nt = 0; nt < 4; ++nt)
#pragma unroll
        for (int rr = 0; rr < 4; ++rr)
          sacc[nt][rr] = sacc[nt][rr] * a.scale + bf2f(Qp[wave][quad * 4 + rr][nt * 16 + lr]);
      if (more) {
        qpr0 = *(const uint4*)(QPr + kt0 + (t + 1) * 64 + qc);
        qpr1 = *(const uint4*)(QPr + kt0 + (t + 1) * 64 + qc + 8);
      }
    } else {
#pragma unroll
      for (int nt = 0; nt < 4; ++nt)
#pragma unroll
        for (int rr = 0; rr < 4; ++rr) sacc[nt][rr] *= a.scale;
    }
    // online softmax (rows replicated across the 16 lanes of a quad)
#pragma unroll
    for (int rr = 0; rr < 4; ++rr) {
      float m = -1e30f;
#pragma unroll
      for (int nt = 0; nt < 4; ++nt) m = fmaxf(m, sacc[nt][rr]);
      for (int o = 8; o > 0; o >>= 1) m = fmaxf(m, __shfl_xor(m, o, 64));
      float mn = fmaxf(m_run[rr], m);
      float al = __expf(m_run[rr] - mn);
      m_run[rr] = mn;
      float s = 0.f;
#pragma unroll
      for (int nt = 0; nt < 4; ++nt) {
        float p = __expf(sacc[nt][rr] - mn);
        sacc[nt][rr] = p;
        s += p;
      }
      for (int o = 8; o > 0; o >>= 1) s += __shfl_xor(s, o, 64);
      l_run[rr] = l_run[rr] * al + s;
#pragma unroll
      for (int nt = 0; nt < 4; ++nt) oacc[nt][rr] *= al;
    }
    // P (C-layout) -> LDS -> A-layout (wave-private)
#pragma unroll
    for (int nt = 0; nt < 4; ++nt) {
      Ps[wave][quad * 4 + 0][nt * 16 + lr] = to_bf16(sacc[nt][0]);
      Ps[wave][quad * 4 + 1][nt * 16 + lr] = to_bf16(sacc[nt][1]);
      Ps[wave][quad * 4 + 2][nt * 16 + lr] = to_bf16(sacc[nt][2]);
      Ps[wave][quad * 4 + 3][nt * 16 + lr] = to_bf16(sacc[nt][3]);
    }
#pragma unroll
    for (int ks = 0; ks < 2; ++ks) {
      int kq = ks * 32 + quad * 8;
      bf16x8 av = *(const bf16x8*)&Ps[wave][lr][kq];
#pragma unroll
      for (int nt = 0; nt < 4; ++nt) {
        bf16x8 bb = *(const bf16x8*)&Vs[cur][nt * 16 + lr][kq];
        oacc[nt] = __builtin_amdgcn_mfma_f32_16x16x32_bf16(av, bb, oacc[nt], 0, 0, 0);
      }
    }
    if (more) {  // stage prefetched tile into the other buffer
      *(uint4*)&Ks[cur ^ 1][r][c] = pk0; *(uint4*)&Ks[cur ^ 1][r][c + 8] = pk1;
      *(uint4*)&Vs[cur ^ 1][r][c] = pv0; *(uint4*)&Vs[cur ^ 1][r][c + 8] = pv1;
    }
  }
  if (a.nsplit == 1) {
    float inv[4];
#pragma unroll
    for (int rr = 0; rr < 4; ++rr) inv[rr] = 1.f / l_run[rr];
#pragma unroll
    for (int nt = 0; nt < 4; ++nt)
#pragma unroll
      for (int rr = 0; rr < 4; ++rr) {
        long row = b * 512 + qt * 64 + wave * 16 + quad * 4 + rr;
        float v = oacc[nt][rr] * inv[rr];
        if (a.obf16) ((u16*)a.O)[row * 512 + h * 64 + nt * 16 + lr] = to_bf16(v);
        else ((float*)a.O)[row * 512 + h * 64 + nt * 16 + lr] = v;
      }
  } else {
#pragma unroll
    for (int nt = 0; nt < 4; ++nt)
#pragma unroll
      for (int rr = 0; rr < 4; ++rr) {
        long row = b * 512 + qt * 64 + wave * 16 + quad * 4 + rr;
        a.Opart[((long)sp * 2048 + row) * 512 + h * 64 + nt * 16 + lr] = oacc[nt][rr];
      }
    if (lr == 0)
#pragma unroll
      for (int rr = 0; rr < 4; ++rr) {
        long row = b * 512 + qt * 64 + wave * 16 + quad * 4 + rr;
        long mi = (((long)sp * 2048 + row) * 8 + h) * 2;
        a.ml[mi] = m_run[rr]; a.ml[mi + 1] = l_run[rr];
      }
  }
}

__global__ __launch_bounds__(256) void embed_k(const int* __restrict__ trg,
                                               const float* __restrict__ embed,
                                               float* __restrict__ x) {
  int i = blockIdx.x * 256 + threadIdx.x;
  int row = i >> 9, d = i & 511;
  x[i] = embed[(long)trg[row] * 512 + d];
}

__global__ __launch_bounds__(256) void concat_kv_k(const float* __restrict__ cmem,
                                                   const float* __restrict__ mem,
                                                   const float* __restrict__ x,
                                                   u16* __restrict__ kv) {
  long i = (long)blockIdx.x * 256 + threadIdx.x;
  int d = i & 511;
  long t = (i >> 9) % 1152;
  long b = (i >> 9) / 1152;
  float v;
  if (t < 128) v = cmem[(b * 128 + t) * 512 + d];
  else if (t < 640) v = mem[(b * 512 + (t - 128)) * 512 + d];
  else v = x[(b * 512 + (t - 640)) * 512 + d];
  kv[i] = to_bf16(v);
}

__global__ __launch_bounds__(256) void layernorm_k(const float* __restrict__ X,
                                                   const float* __restrict__ g,
                                                   const float* __restrict__ b,
                                                   u16* __restrict__ Y) {
  long row = blockIdx.x;
  const float* x = X + row * 512;
  int tid = threadIdx.x;
  float v0 = x[tid], v1 = x[tid + 256];
  __shared__ float red[256];
  red[tid] = v0 + v1; __syncthreads();
  for (int o = 128; o > 0; o >>= 1) { if (tid < o) red[tid] += red[tid + o]; __syncthreads(); }
  float mu = red[0] * (1.f / 512.f);
  __syncthreads();
  float d0 = v0 - mu, d1 = v1 - mu;
  red[tid] = d0 * d0 + d1 * d1; __syncthreads();
  for (int o = 128; o > 0; o >>= 1) { if (tid < o) red[tid] += red[tid + o]; __syncthreads(); }
  float rstd = rsqrtf(red[0] * (1.f / 512.f) + 1e-5f);
  Y[row * 512 + tid] = to_bf16(d0 * rstd * g[tid] + b[tid]);
  Y[row * 512 + tid + 256] = to_bf16(d1 * rstd * g[tid + 256] + b[tid + 256]);
}

__global__ __launch_bounds__(256) void preset_k(float* __restrict__ C,
                                                const float* __restrict__ res,
                                                const float* __restrict__ bias, int nmask) {
  long i = (long)blockIdx.x * 256 + threadIdx.x;
  float v = 0.f;
  if (res) v += res[i];
  if (bias) v += bias[i & nmask];
  C[i] = v;
}

// loss with fused 2-way flash-split combine for the "old mem" side
__global__ __launch_bounds__(256) void loss2_k(const float* __restrict__ ocm,
                                               const float* __restrict__ Opart,
                                               const float* __restrict__ ml,
                                               float* __restrict__ acc) {
  float s = 0.f;
  for (long i = (long)blockIdx.x * 256 + threadIdx.x; i < 1048576; i += 256L * 128) {
    int row = (int)(i >> 9), col = (int)(i & 511), h = col >> 6;
    const float* mlp = ml + ((long)row * 8 + h) * 2;
    float m0v = mlp[0], l0v = mlp[1];
    float m1v = mlp[32768], l1v = mlp[32769];
    float mm = fmaxf(m0v, m1v);
    float w0 = __expf(m0v - mm), w1 = __expf(m1v - mm);
    float ov = (w0 * Opart[i] + w1 * Opart[1048576 + i]) / (w0 * l0v + w1 * l1v);
    float d = ocm[i] - ov; s += d * d;
  }
  for (int o = 32; o > 0; o >>= 1) s += __shfl_xor(s, o, 64);
  __shared__ float red[4];
  if ((threadIdx.x & 63) == 0) red[threadIdx.x >> 6] = s;
  __syncthreads();
  if (threadIdx.x == 0) atomicAdd(acc, red[0] + red[1] + red[2] + red[3]);
}

__global__ __launch_bounds__(256) void transpose_bf16_k(const float* __restrict__ in,
                                                        u16* __restrict__ out, int K, int N) {
  long z = blockIdx.z;
  in += z * (long)K * N; out += z * (long)K * N;
  __shared__ float t[32][33];
  int n0 = blockIdx.x * 32, k0 = blockIdx.y * 32;
  int tx = threadIdx.x, ty = threadIdx.y;
  for (int j = 0; j < 32; j += 8) t[ty + j][tx] = in[(long)(k0 + ty + j) * N + n0 + tx];
  __syncthreads();
  for (int j = 0; j < 32; j += 8) out[(long)(n0 + ty + j) * K + k0 + tx] = to_bf16(t[tx][ty + j]);
}

__global__ __launch_bounds__(256) void convw_k(const float* __restrict__ in,
                                               u16* __restrict__ out) {
  int i = blockIdx.x * 256 + threadIdx.x;
  long z = blockIdx.z;
  int o = i >> 11, k = i & 2047;
  int r = k >> 9, d = k & 511;
  out[z * 1048576 + i] = to_bf16(in[z * 1048576 + o * 2048 + d * 4 + r]);
}

__global__ __launch_bounds__(256) void cvt_bf16_k(const float* __restrict__ in,
                                                  u16* __restrict__ out, int n) {
  int i = blockIdx.x * 256 + threadIdx.x;
  if (i < n) out[i] = to_bf16(in[i]);
}

__global__ __launch_bounds__(256) void finalize_k(const float* __restrict__ x,
                                                  const float* __restrict__ loss,
                                                  float* __restrict__ out) {
  long i = (long)blockIdx.x * 256 + threadIdx.x;
  if (i < 1048576) out[i] = x[i];
  else if (i == 1048576) out[i] = loss[0] * (1.f / (1048576.f * 4.f));
}

extern "C" void kernel_launch(void* const* d_in, const int* in_sizes, int n_in,
                              void* d_out, int out_size, void* d_ws, size_t ws_size,
                              hipStream_t stream) {
  (void)in_sizes; (void)n_in; (void)out_size;
  const int* trg = (const int*)d_in[0];
  const float* latent = (const float*)d_in[3];
  const float* mems = (const float*)d_in[4];
  const float* cmems = (const float*)d_in[5];
  const float* pos_emb = (const float*)d_in[6];
  const float* embed = (const float*)d_in[7];
  const float* W_self = (const float*)d_in[8];
  const float* ln1_g = (const float*)d_in[9];
  const float* ln1_b = (const float*)d_in[10];
  const float* conv_w = (const float*)d_in[11];
  const float* conv_b = (const float*)d_in[12];
  const float* W_src = (const float*)d_in[13];
  const float* ln2_g = (const float*)d_in[14];
  const float* ln2_b = (const float*)d_in[15];
  const float* w1 = (const float*)d_in[16];
  const float* b1 = (const float*)d_in[17];
  const float* w2 = (const float*)d_in[18];
  const float* b2 = (const float*)d_in[19];

  float* ws = (float*)d_ws;
  long off = 0;
  auto alloc = [&](long n) { float* p = ws + off; off += (n + 63) & ~63L; return p; };
  float* x    = alloc(1048576);
  float* t0   = alloc(1048576);
  float* t1   = alloc(1048576);
  float* ncm  = alloc(262144);
  float* ocm  = alloc(1048576);
  float* Opart= alloc(2097152);       // aliases h1 (disjoint liveness: attn vs FF)
  u16* h1   = (u16*)Opart;            // [2048][2048] bf16
  float* mlb  = alloc(65536);         // [2][2048][8][2]
  float* Opart2 = alloc(2097152);     // cross-attn partials (co-runs with oold)
  float* mlb2 = alloc(65536);
  // [2048][512] bf16 buffers need 1048576 u16 = 524288 floats each
  u16* qb   = (u16*)alloc(524288);
  u16* qc   = (u16*)alloc(524288);
  u16* xa   = (u16*)alloc(524288);
  u16* t1h  = (u16*)alloc(524288);
  u16* kvcat= (u16*)alloc(1179648);
  u16* kbuf = (u16*)alloc(1179648);
  u16* vbuf = (u16*)alloc(1179648);
  u16* kmem = (u16*)alloc(524288);    // rattn target K proj
  u16* vmem = (u16*)alloc(524288);    // rattn target V proj (transposed, ldc=2048)
  u16* kcm  = (u16*)alloc(131072);
  u16* vcm  = (u16*)alloc(131072);
  u16* klat = (u16*)alloc(262144);
  u16* vlat = (u16*)alloc(262144);
  u16* SQP  = (u16*)alloc(9437184);   // [4][8][512][1152] bf16 pre-shifted, *8 folded
  u16* wts  = (u16*)alloc(2097152);
  u16* wsr  = (u16*)alloc(2097152);
  u16* w1t  = (u16*)alloc(2097152);
  u16* w2t  = (u16*)alloc(2097152);
  u16* cwt  = (u16*)alloc(2097152);
  u16* post = (u16*)alloc(294912);
  float* lossacc = alloc(64);
  if ((size_t)off * 4 > ws_size) return;

  hipMemsetAsync(lossacc, 0, 4, stream);
  hipMemsetAsync(SQP, 0, 37748736, stream);  // tail region (k>=641+q) is never scattered
  embed_k<<<4096, 256, 0, stream>>>(trg, embed, x);
  transpose_bf16_k<<<dim3(16, 16, 16), dim3(32, 8), 0, stream>>>(W_self, wts, 512, 512);
  transpose_bf16_k<<<dim3(16, 16, 16), dim3(32, 8), 0, stream>>>(W_src, wsr, 512, 512);
  transpose_bf16_k<<<dim3(64, 16, 4), dim3(32, 8), 0, stream>>>(w1, w1t, 512, 2048);
  transpose_bf16_k<<<dim3(16, 64, 4), dim3(32, 8), 0, stream>>>(w2, w2t, 2048, 512);
  convw_k<<<dim3(4096, 1, 4), 256, 0, stream>>>(conv_w, cwt);
  cvt_bf16_k<<<2304, 256, 0, stream>>>(pos_emb, post, 589824);

  auto ga = []() { GemmArgs g; g.alpha = 1.f; g.bias = nullptr; g.res = nullptr; g.ldres = 512;
                   g.aml = nullptr;
                   g.amode = 0; g.cmode = 0; g.act = 0; g.smode = 0; g.bdiv = 1; g.kparts = 1;
                   g.sA1 = g.sA2 = g.sB1 = g.sB2 = g.sC1 = g.sC2 = 0; g.N = 0;
                   g.gx = g.gy = 1; return g; };
  GemmBatch GB; GB.ng = 0; int gtot = 0;
  auto badd = [&](GemmArgs g, int gx, int gy, int gz) {
    g.gx = gx; g.gy = gy;
    GB.g[GB.ng] = g; gtot += gx * gy * gz; GB.end[GB.ng] = gtot; GB.ng++;
  };
  auto brun = [&]() {
    gemmb_k<<<dim3(gtot), 256, 0, stream>>>(GB);
    GB.ng = 0; gtot = 0;
  };
  auto run1 = [&](GemmArgs g, int gx, int gy, int gz) { badd(g, gx, gy, gz); brun(); };

  FBatch FB; FB.nf = 0; int ztot = 0;
  auto fadd = [&](const u16* Q, const u16* K, const u16* V, const u16* QP, void* O,
                  int L, int nsplit, long sKb, long sVb, int ldV, int obf16,
                  float* Op, float* ml) {
    FAttnArgs a; a.Q = Q; a.K = K; a.V = V; a.QP = QP; a.O = O;
    a.Opart = Op; a.ml = ml;
    a.L = L; a.nsplit = nsplit; a.sKb = sKb; a.sVb = sVb; a.ldV = ldV;
    a.scale = 0.125f; a.obf16 = obf16;
    FB.a[FB.nf] = a; ztot += 4 * nsplit; FB.zend[FB.nf] = ztot; FB.nf++;
  };
  auto frun = [&]() {
    fattnb_k<<<dim3(8, 8, ztot), 256, 0, stream>>>(FB);
    FB.nf = 0; ztot = 0;
  };

  for (int l = 0; l < 4; ++l) {
    const u16* Wt0 = wts + (l * 4 + 0) * 262144;
    const u16* Wt1 = wts + (l * 4 + 1) * 262144;
    const u16* Wt2 = wts + (l * 4 + 2) * 262144;
    const u16* Wt3 = wts + (l * 4 + 3) * 262144;
    const u16* Ws0 = wsr + (l * 4 + 0) * 262144;
    const u16* Ws1 = wsr + (l * 4 + 1) * 262144;
    const u16* Ws2 = wsr + (l * 4 + 2) * 262144;
    const u16* Ws3 = wsr + (l * 4 + 3) * 262144;
    const float* mem_l = mems + (long)l * 1048576;
    const float* cmem_l = cmems + (long)l * 262144;

    // ===== prep: everything that depends only on layer inputs =====
    concat_kv_k<<<9216, 256, 0, stream>>>(cmem_l, mem_l, x, kvcat);
    preset_k<<<1024, 256, 0, stream>>>(ncm, nullptr, conv_b + l * 512, 511);
    // batchP: {qb, conv->ncm, kmem, vmem, klat, vlat} = 1536 blocks
    { GemmArgs g = ga(); g.A = x; g.lda = 512; g.B = Wt0; g.ldb = 512; g.C = qb; g.ldc = 512;
      g.cmode = 1; g.Kc = 512; badd(g, 8, 32, 1); }
    { GemmArgs g = ga(); g.A = mem_l; g.lda = 2048; g.B = cwt + (long)l * 1048576; g.ldb = 2048;
      g.C = ncm; g.ldc = 512; g.cmode = 3; g.kparts = 8; g.Kc = 256; badd(g, 8, 8, 8); }
    { GemmArgs g = ga(); g.A = mem_l; g.lda = 512; g.B = Wt1; g.ldb = 512;
      g.C = kmem; g.ldc = 512; g.cmode = 1; g.Kc = 512; badd(g, 8, 32, 1); }
    { GemmArgs g = ga(); g.A = mem_l; g.lda = 512; g.B = Wt2; g.ldb = 512;
      g.C = vmem; g.ldc = 2048; g.cmode = 2; g.Kc = 512; badd(g, 8, 32, 1); }
    { GemmArgs g = ga(); g.A = latent; g.lda = 512; g.B = Ws1; g.ldb = 512;
      g.C = klat; g.ldc = 512; g.cmode = 1; g.Kc = 512; badd(g, 8, 16, 1); }
    { GemmArgs g = ga(); g.A = latent; g.lda = 512; g.B = Ws2; g.ldb = 512;
      g.C = vlat; g.ldc = 1024; g.cmode = 2; g.Kc = 512; badd(g, 8, 16, 1); }
    brun();

    // batch1: {kbuf, vbuf, kcm, vcm, SQP-scatter} = 5888 blocks
    { GemmArgs g = ga(); g.A = kvcat; g.amode = 1; g.lda = 512; g.B = Wt1; g.ldb = 512;
      g.C = kbuf; g.ldc = 512; g.cmode = 1; g.Kc = 512; badd(g, 8, 72, 1); }
    { GemmArgs g = ga(); g.A = kvcat; g.amode = 1; g.lda = 512; g.sA1 = 589824; g.B = Wt2; g.ldb = 512;
      g.C = vbuf; g.ldc = 1152; g.sC1 = 589824; g.cmode = 2; g.Kc = 512; badd(g, 8, 18, 4); }
    { GemmArgs g = ga(); g.A = ncm; g.lda = 512; g.B = Wt1; g.ldb = 512;
      g.C = kcm; g.ldc = 512; g.cmode = 1; g.Kc = 512; badd(g, 8, 8, 1); }
    { GemmArgs g = ga(); g.A = ncm; g.lda = 512; g.B = Wt2; g.ldb = 512;
      g.C = vcm; g.ldc = 512; g.cmode = 2; g.Kc = 512; badd(g, 8, 8, 1); }
    // SQP[b][h][q][k] = 8*(q . pos[h][k+511-q]) via shifted scatter epilogue, bf16
    { GemmArgs g = ga(); g.A = qb; g.amode = 1; g.lda = 512; g.sA1 = 262144; g.sA2 = 64;
      g.B = post; g.ldb = 64; g.sB1 = 0; g.sB2 = 73728;
      g.C = SQP; g.ldc = 1152; g.sC1 = 4718592; g.sC2 = 589824;
      g.smode = 1; g.alpha = 8.f; g.bdiv = 8; g.Kc = 64; badd(g, 18, 8, 32); }
    brun();

    // ===== self-attention (combine fused into attnout GEMM A-staging) =====
    fadd(qb, kbuf, vbuf, SQP, nullptr, 1152, 2, 589824, 589824, 1152, 1, Opart, mlb);
    frun();
    { GemmArgs g = ga(); g.A = Opart; g.amode = 2; g.aml = mlb; g.lda = 512; g.sA1 = 1048576;
      g.B = Wt3; g.ldb = 512; g.C = t1; g.ldc = 512; g.res = x; g.Kc = 512; run1(g, 8, 32, 1); }
    layernorm_k<<<2048, 256, 0, stream>>>(t1, ln1_g + l * 512, ln1_b + l * 512, xa);

    // batchQ: {rattn Q, cross Q} (both from xa)
    { GemmArgs g = ga(); g.A = xa; g.amode = 1; g.lda = 512; g.B = Wt0; g.ldb = 512;
      g.C = qb; g.ldc = 512; g.cmode = 1; g.Kc = 512; badd(g, 8, 32, 1); }
    { GemmArgs g = ga(); g.A = xa; g.amode = 1; g.lda = 512; g.B = Ws0; g.ldb = 512;
      g.C = qc; g.ldc = 512; g.cmode = 1; g.Kc = 512; badd(g, 8, 32, 1); }
    brun();

    // ===== rattn (compression loss) + cross attention, one batched launch =====
    fadd(qb, kcm, vcm, nullptr, ocm, 128, 1, 65536, 128, 512, 0, Opart, mlb);
    fadd(qb, kmem, vmem, nullptr, nullptr, 512, 2, 262144, 512, 2048, 0, Opart, mlb);
    fadd(qc, klat, vlat, nullptr, nullptr, 256, 2, 131072, 256, 1024, 1, Opart2, mlb2);
    frun();
    loss2_k<<<128, 256, 0, stream>>>(ocm, Opart, mlb, lossacc);

    { GemmArgs g = ga(); g.A = Opart2; g.amode = 2; g.aml = mlb2; g.lda = 512; g.sA1 = 1048576;
      g.B = Ws3; g.ldb = 512; g.C = t0; g.ldc = 512; g.Kc = 512; run1(g, 8, 32, 1); }
    layernorm_k<<<2048, 256, 0, stream>>>(t0, ln2_g + l * 512, ln2_b + l * 512, t1h);

    // ===== FF =====
    { GemmArgs g = ga(); g.A = t1h; g.amode = 1; g.lda = 512; g.B = w1t + (long)l * 1048576; g.ldb = 512;
      g.C = h1; g.ldc = 2048; g.cmode = 1; g.bias = b1 + l * 2048; g.act = 1; g.Kc = 512;
      run1(g, 32, 32, 1); }
    preset_k<<<4096, 256, 0, stream>>>(x, t0, b2 + l * 512, 511);
    { GemmArgs g = ga(); g.A = h1; g.amode = 1; g.lda = 2048; g.B = w2t + (long)l * 1048576; g.ldb = 2048;
      g.C = x; g.ldc = 512; g.cmode = 3; g.kparts = 4; g.Kc = 512; run1(g, 8, 32, 4); }
  }
  finalize_k<<<4097, 256, 0, stream>>>(x, lossacc, (float*)d_out);
}

// Round 3
// 1133.648 us; speedup vs baseline: 1.3609x; 1.0239x over previous
//
#include <hip/hip_runtime.h>
#include <math.h>

typedef float floatx4 __attribute__((ext_vector_type(4)));
typedef __bf16 bf16x8 __attribute__((ext_vector_type(8)));
typedef unsigned short u16;

#define LDK 72  // LDS row stride in ushorts for fattn (144B, 16B-aligned)

__device__ inline u16 to_bf16(float f) {
  union { float f; unsigned u; } v; v.f = f;
  unsigned u = v.u;
  u += 0x7FFFu + ((u >> 16) & 1u);
  return (u16)(u >> 16);
}
__device__ inline float bf2f(u16 h) {
  union { unsigned u; float f; } v; v.u = ((unsigned)h) << 16; return v.f;
}

// async global->LDS, 16B per lane. LDS dest must be wave-uniform base
// (HW adds lane*16). Swizzled LDS content achieved by pre-swizzling the
// per-lane GLOBAL source address (rule #21: both-sides-or-neither).
__device__ inline void gload16(const void* g, void* l) {
  __builtin_amdgcn_global_load_lds(
      (const __attribute__((address_space(1))) unsigned int*)g,
      (__attribute__((address_space(3))) unsigned int*)l, 16, 0, 0);
}

struct GemmArgs {
  const void* A; const void* B; void* C;
  int lda, ldb, ldc, N, Kc;   // N = nsplit for amode=2
  long sA1, sA2, sB1, sB2, sC1, sC2;
  float alpha;
  const float* bias;
  const float* res; int ldres;
  const float* aml;  // amode=2/9: ml buffer [ns][2048][8][2]
  int amode;   // 0: A fp32, 1: A bf16, 2: A = flash-split combine,
               // 8: elementwise preset C=res+bias, 9: loss reduction
  int cmode;   // 0: fp32 C, 1: bf16 C, 2: bf16 C transposed, 3: fp32 atomicAdd
  int act;     // exact gelu
  int smode;   // shifted bf16 scatter: C[row][col+row-511] = bf16(v) if >=0
  int bdiv, kparts;
  int gx, gy;  // grid decomposition of this descriptor's block range
};

#define MAXG 10
struct GemmBatch {
  GemmArgs g[MAXG];
  int end[MAXG];   // cumulative block-count ends
  int ng;
};

// Grouped GEMM, 64x64 tile, K-step 64 + elementwise/loss descriptor modes.
__global__ __launch_bounds__(256) void gemmb_k(GemmBatch gb) {
  int bid = blockIdx.x;
  int gi = 0;
  while (bid >= gb.end[gi]) ++gi;
  const GemmArgs g = gb.g[gi];
  int lb = bid - (gi ? gb.end[gi - 1] : 0);
  int tid = threadIdx.x;

  if (g.amode == 8) {  // elementwise preset: C[i] = res[i] + bias[i&511]
    long i = (long)lb * 1024 + tid * 4;
    const float* bs = g.bias;
    int bi = (int)(i & 511);
    float4 r = *(const float4*)(g.res + i);
    float4 v;
    v.x = r.x + bs[bi]; v.y = r.y + bs[bi + 1];
    v.z = r.z + bs[bi + 2]; v.w = r.w + bs[bi + 3];
    *(float4*)((float*)g.C + i) = v;
    return;
  }
  if (g.amode == 9) {  // MSE loss with fused 2-way flash combine (ex loss2_k)
    const float* oc = (const float*)g.A;
    const float* Op = (const float*)g.B;
    const float* ml = g.aml;
    float s = 0.f;
    for (long i = (long)lb * 256 + tid; i < 1048576; i += 256L * g.gx) {
      int row = (int)(i >> 9), col = (int)(i & 511), h = col >> 6;
      const float* mlp = ml + ((long)row * 8 + h) * 2;
      float m0v = mlp[0], l0v = mlp[1];
      float m1v = mlp[32768], l1v = mlp[32769];
      float mm = fmaxf(m0v, m1v);
      float w0 = __expf(m0v - mm), w1 = __expf(m1v - mm);
      float ov = (w0 * Op[i] + w1 * Op[1048576 + i]) / (w0 * l0v + w1 * l1v);
      float d = oc[i] - ov; s += d * d;
    }
    for (int o = 32; o > 0; o >>= 1) s += __shfl_xor(s, o, 64);
    __shared__ float red[4];
    if ((tid & 63) == 0) red[tid >> 6] = s;
    __syncthreads();
    if (tid == 0) atomicAdd((float*)g.C, red[0] + red[1] + red[2] + red[3]);
    return;
  }

  int bx = lb % g.gx;
  int rem = lb / g.gx;
  int by = rem % g.gy;
  int z = rem / g.gy;

  int kp = z % g.kparts;
  int zz = z / g.kparts;
  int zi = zz / g.bdiv, zj = zz % g.bdiv;
  long aoff = (long)zi * g.sA1 + (long)zj * g.sA2;
  long boff = (long)zi * g.sB1 + (long)zj * g.sB2;
  long coff = (long)zi * g.sC1 + (long)zj * g.sC2;
  const float* Af = (const float*)g.A + aoff;
  const u16* Ah = (const u16*)g.A + aoff;
  const u16* Bh = (const u16*)g.B + boff;

  int m0 = by * 64, n0 = bx * 64;
  __shared__ u16 As[64][64];
  __shared__ u16 Bs[64][64];
  char* Asb = (char*)&As[0][0];
  char* Bsb = (char*)&Bs[0][0];
  int wave = tid >> 6, lane = tid & 63;
  int wr = (wave >> 1) * 32, wc = (wave & 1) * 32;
  int lr = lane & 15, qrow = lane >> 4;

  // async-staging geometry: lane covers LDS bytes o (linear); its global
  // source is the logical element whose swizzle lands at o.
  unsigned o0 = wave * 1024u + lane * 16u;
  unsigned o1 = o0 + 4096u;
  int ga_r0 = o0 >> 7, ga_r1 = o1 >> 7;
  int ga_c0 = (int)(o0 & 127u) ^ ((ga_r0 & 7) << 4);
  int ga_c1 = (int)(o1 & 127u) ^ ((ga_r1 & 7) << 4);
  long ldaB = (long)g.lda * 2, ldbB = (long)g.ldb * 2;
  // reg-staging geometry
  int r = tid >> 2, c16 = (tid & 3) << 4;
  int sw0 = (r << 7) + (((tid & 3) << 5) ^ ((r & 7) << 4));
  int sw1 = (r << 7) + ((((tid & 3) << 5) + 16) ^ ((r & 7) << 4));

  floatx4 acc[2][2];
#pragma unroll
  for (int i = 0; i < 2; ++i)
#pragma unroll
    for (int j = 0; j < 2; ++j)
#pragma unroll
      for (int rr = 0; rr < 4; ++rr) acc[i][j][rr] = 0.f;

  int kb0 = kp * g.Kc, kb1 = kb0 + g.Kc;
  for (int k0 = kb0; k0 < kb1; k0 += 64) {
    if (g.amode == 1) {
      const char* Ab = (const char*)Ah + ((long)m0 * g.lda + k0) * 2;
      gload16(Ab + ga_r0 * ldaB + ga_c0, Asb + wave * 1024);
      gload16(Ab + ga_r1 * ldaB + ga_c1, Asb + 4096 + wave * 1024);
    } else if (g.amode == 0) {
      const float* ap = Af + (long)(m0 + r) * g.lda + k0 + c16;
      float4 a0 = *(const float4*)ap, a1 = *(const float4*)(ap + 4);
      float4 a2 = *(const float4*)(ap + 8), a3 = *(const float4*)(ap + 12);
      union { u16 s[8]; uint4 v; } u0, u1;
      u0.s[0] = to_bf16(a0.x); u0.s[1] = to_bf16(a0.y); u0.s[2] = to_bf16(a0.z); u0.s[3] = to_bf16(a0.w);
      u0.s[4] = to_bf16(a1.x); u0.s[5] = to_bf16(a1.y); u0.s[6] = to_bf16(a1.z); u0.s[7] = to_bf16(a1.w);
      u1.s[0] = to_bf16(a2.x); u1.s[1] = to_bf16(a2.y); u1.s[2] = to_bf16(a2.z); u1.s[3] = to_bf16(a2.w);
      u1.s[4] = to_bf16(a3.x); u1.s[5] = to_bf16(a3.y); u1.s[6] = to_bf16(a3.z); u1.s[7] = to_bf16(a3.w);
      *(uint4*)(Asb + sw0) = u0.v; *(uint4*)(Asb + sw1) = u1.v;
    } else {  // amode 2: A = combine of g.N flash splits (ex-fcomb, fused)
      int row = m0 + r;
      int k = k0 + c16;               // all 16 cols in one head (k0%64==0)
      int ns = g.N;
      const float* mlp = g.aml + ((long)row * 8 + (k >> 6)) * 2;
      float mm = -1e30f;
#pragma unroll 3
      for (int s = 0; s < 3; ++s)
        if (s < ns) mm = fmaxf(mm, mlp[s * 32768]);
      float wgt[3]; float den = 0.f;
#pragma unroll 3
      for (int s = 0; s < 3; ++s)
        if (s < ns) { wgt[s] = __expf(mlp[s * 32768] - mm); den += wgt[s] * mlp[s * 32768 + 1]; }
      float inv = 1.f / den;
      float a16[16];
#pragma unroll
      for (int j = 0; j < 16; ++j) a16[j] = 0.f;
      const float* p0 = (const float*)g.A + (long)row * g.lda + k;
#pragma unroll 3
      for (int s = 0; s < 3; ++s)
        if (s < ns) {
          float w = wgt[s] * inv;
          const float* p = p0 + (long)s * g.sA1;
#pragma unroll
          for (int j = 0; j < 4; ++j) {
            float4 xx = *(const float4*)(p + j * 4);
            a16[j * 4 + 0] += w * xx.x; a16[j * 4 + 1] += w * xx.y;
            a16[j * 4 + 2] += w * xx.z; a16[j * 4 + 3] += w * xx.w;
          }
        }
      union { u16 s[8]; uint4 v; } u0, u1;
#pragma unroll
      for (int j = 0; j < 8; ++j) u0.s[j] = to_bf16(a16[j]);
#pragma unroll
      for (int j = 0; j < 8; ++j) u1.s[j] = to_bf16(a16[8 + j]);
      *(uint4*)(Asb + sw0) = u0.v; *(uint4*)(Asb + sw1) = u1.v;
    }
    {
      const char* Bb = (const char*)Bh + ((long)n0 * g.ldb + k0) * 2;
      gload16(Bb + ga_r0 * ldbB + ga_c0, Bsb + wave * 1024);
      gload16(Bb + ga_r1 * ldbB + ga_c1, Bsb + 4096 + wave * 1024);
    }
    __syncthreads();   // drains vmcnt (gload) + lgkm (ds_write)
#pragma unroll
    for (int ks = 0; ks < 2; ++ks) {
      int xk = ((ks * 32 + qrow * 8) << 1) ^ ((lr & 7) << 4);
      int rA0 = wr + lr, rB0 = wc + lr;
      bf16x8 a0 = *(const bf16x8*)(Asb + (rA0 << 7) + xk);
      bf16x8 a1 = *(const bf16x8*)(Asb + ((rA0 + 16) << 7) + xk);
      bf16x8 b0 = *(const bf16x8*)(Bsb + (rB0 << 7) + xk);
      bf16x8 b1 = *(const bf16x8*)(Bsb + ((rB0 + 16) << 7) + xk);
      acc[0][0] = __builtin_amdgcn_mfma_f32_16x16x32_bf16(a0, b0, acc[0][0], 0, 0, 0);
      acc[0][1] = __builtin_amdgcn_mfma_f32_16x16x32_bf16(a0, b1, acc[0][1], 0, 0, 0);
      acc[1][0] = __builtin_amdgcn_mfma_f32_16x16x32_bf16(a1, b0, acc[1][0], 0, 0, 0);
      acc[1][1] = __builtin_amdgcn_mfma_f32_16x16x32_bf16(a1, b1, acc[1][1], 0, 0, 0);
    }
    __syncthreads();
  }

#pragma unroll
  for (int mt = 0; mt < 2; ++mt)
#pragma unroll
    for (int nt = 0; nt < 2; ++nt) {
      int row0 = m0 + wr + mt * 16 + qrow * 4;
      int col = n0 + wc + nt * 16 + lr;
      if (g.cmode == 2) {
        ushort4 o;
        o.x = to_bf16(acc[mt][nt][0] * g.alpha);
        o.y = to_bf16(acc[mt][nt][1] * g.alpha);
        o.z = to_bf16(acc[mt][nt][2] * g.alpha);
        o.w = to_bf16(acc[mt][nt][3] * g.alpha);
        *(ushort4*)((u16*)g.C + coff + (long)col * g.ldc + row0) = o;
      } else {
#pragma unroll
        for (int rr = 0; rr < 4; ++rr) {
          int row = row0 + rr;
          float v = acc[mt][nt][rr] * g.alpha;
          if (g.cmode == 3) {
            atomicAdd((float*)g.C + coff + (long)row * g.ldc + col, v);
          } else if (g.smode) {
            int oc = col + row - 511;
            if (oc >= 0) ((u16*)g.C + coff)[(long)row * g.ldc + oc] = to_bf16(v);
          } else {
            if (g.bias) v += g.bias[col];
            if (g.res) v += g.res[(long)row * g.ldres + col];
            if (g.act) v = 0.5f * v * (1.0f + erff(v * 0.70710678118654752f));
            if (g.cmode == 1) ((u16*)g.C + coff)[(long)row * g.ldc + col] = to_bf16(v);
            else ((float*)g.C + coff)[(long)row * g.ldc + col] = v;
          }
        }
      }
    }
}

struct FAttnArgs {
  const u16* Q; const u16* K; const u16* V; const u16* QP;  // QP = pre-shifted SQP
  void* O; float* Opart; float* ml;
  int L, nsplit; long sKb, sVb; int ldV;
  float scale; int obf16;
};

struct FBatch {
  FAttnArgs a[3];
  int zend[3];  // cumulative z ends
  int nf;
};

// Fused flash attention, double-buffered K/V, optional pre-shifted pos bias,
// optional KV-split (unnormalized partials + m/l; combine fused in consumers).
__global__ __launch_bounds__(256) void fattnb_k(FBatch fb) {
  int zg = blockIdx.z;
  int fi = 0;
  while (zg >= fb.zend[fi]) ++fi;
  const FAttnArgs a = fb.a[fi];
  int zl = zg - (fi ? fb.zend[fi - 1] : 0);

  int qt = blockIdx.x, h = blockIdx.y;
  int b = zl / a.nsplit, sp = zl % a.nsplit;
  int Lc = a.L / a.nsplit, kt0 = sp * Lc, T = Lc >> 6;
  int tid = threadIdx.x, wave = tid >> 6, lane = tid & 63;
  int lr = lane & 15, quad = lane >> 4;
  __shared__ u16 Qs[64][LDK];
  __shared__ u16 Ks[2][64][LDK];
  __shared__ u16 Vs[2][64][LDK];
  __shared__ u16 Qp[4][16][LDK];
  __shared__ u16 Ps[4][16][LDK];
  int r = tid >> 2, c = (tid & 3) << 4;
  {
    const u16* qp = a.Q + (long)(b * 512 + qt * 64 + r) * 512 + h * 64 + c;
    *(uint4*)&Qs[r][c] = *(const uint4*)qp;
    *(uint4*)&Qs[r][c + 8] = *(const uint4*)(qp + 8);
  }
  const u16* Kb = a.K + (long)b * a.sKb + h * 64;
  const u16* Vb = a.V + (long)b * a.sVb + (long)(h * 64) * a.ldV;
  int qrow16 = lane >> 2, qc = (lane & 3) << 4;  // wave-private SQP tile loader
  const u16* QPr = a.QP ? a.QP + ((long)b * 8 + h) * 589824 +
                          (long)(qt * 64 + wave * 16 + qrow16) * 1152 : nullptr;
  // preload tile 0 straight into LDS buffer 0
  {
    const u16* kp = Kb + (long)(kt0 + r) * 512 + c;
    *(uint4*)&Ks[0][r][c] = *(const uint4*)kp;
    *(uint4*)&Ks[0][r][c + 8] = *(const uint4*)(kp + 8);
    const u16* vp = Vb + (long)r * a.ldV + kt0 + c;
    *(uint4*)&Vs[0][r][c] = *(const uint4*)vp;
    *(uint4*)&Vs[0][r][c + 8] = *(const uint4*)(vp + 8);
  }
  uint4 qpr0, qpr1;
  if (QPr) {  // 16 u16 per lane: two uint4s
    qpr0 = *(const uint4*)(QPr + kt0 + qc);
    qpr1 = *(const uint4*)(QPr + kt0 + qc + 8);
  }

  float m_run[4], l_run[4];
  floatx4 oacc[4];
#pragma unroll
  for (int i = 0; i < 4; ++i) {
    m_run[i] = -1e30f; l_run[i] = 0.f;
#pragma unroll
    for (int j = 0; j < 4; ++j) oacc[i][j] = 0.f;
  }

  for (int t = 0; t < T; ++t) {
    int cur = t & 1;
    bool more = (t + 1) < T;
    __syncthreads();
    uint4 pk0, pk1, pv0, pv1;
    if (more) {
      int kt = kt0 + (t + 1) * 64;
      const u16* kp = Kb + (long)(kt + r) * 512 + c;
      pk0 = *(const uint4*)kp; pk1 = *(const uint4*)(kp + 8);
      const u16* vp = Vb + (long)r * a.ldV + kt + c;
      pv0 = *(const uint4*)vp; pv1 = *(const uint4*)(vp + 8);
    }
    floatx4 sacc[4];
#pragma unroll
    for (int nt = 0; nt < 4; ++nt)
#pragma unroll
      for (int j = 0; j < 4; ++j) sacc[nt][j] = 0.f;
#pragma unroll
    for (int ks = 0; ks < 2; ++ks) {
      int kq = ks * 32 + quad * 8;
      bf16x8 av = *(const bf16x8*)&Qs[wave * 16 + lr][kq];
#pragma unroll
      for (int nt = 0; nt < 4; ++nt) {
        bf16x8 bb = *(const bf16x8*)&Ks[cur][nt * 16 + lr][kq];
        sacc[nt] = __builtin_amdgcn_mfma_f32_16x16x32_bf16(av, bb, sacc[nt], 0, 0, 0);
      }
    }
    if (QPr) {
      *(uint4*)&Qp[wave][qrow16][qc] = qpr0;
      *(uint4*)&Qp[wave][qrow16][qc + 8] = qpr1;
#pragma unroll
      for (int nt = 0; nt < 4; ++nt)
#pragma unroll
        for (int rr = 0; rr < 4; ++rr)
          sacc[nt][rr] = sacc[nt][rr] * a.scale + bf2f(Qp[wave][quad * 4 + rr][nt * 16 + lr]);
      if (more) {
        qpr0 = *(const uint4*)(QPr + kt0 + (t + 1) * 64 + qc);
        qpr1 = *(const uint4*)(QPr + kt0 + (t + 1) * 64 + qc + 8);
      }
    } else {
#pragma unroll
      for (int nt = 0; nt < 4; ++nt)
#pragma unroll
        for (int rr = 0; rr < 4; ++rr) sacc[nt][rr] *= a.scale;
    }
    // online softmax (rows replicated across the 16 lanes of a quad)
#pragma unroll
    for (int rr = 0; rr < 4; ++rr) {
      float m = -1e30f;
#pragma unroll
      for (int nt = 0; nt < 4; ++nt) m = fmaxf(m, sacc[nt][rr]);
      for (int o = 8; o > 0; o >>= 1) m = fmaxf(m, __shfl_xor(m, o, 64));
      float mn = fmaxf(m_run[rr], m);
      float al = __expf(m_run[rr] - mn);
      m_run[rr] = mn;
      float s = 0.f;
#pragma unroll
      for (int nt = 0; nt < 4; ++nt) {
        float p = __expf(sacc[nt][rr] - mn);
        sacc[nt][rr] = p;
        s += p;
      }
      for (int o = 8; o > 0; o >>= 1) s += __shfl_xor(s, o, 64);
      l_run[rr] = l_run[rr] * al + s;
#pragma unroll
      for (int nt = 0; nt < 4; ++nt) oacc[nt][rr] *= al;
    }
    // P (C-layout) -> LDS -> A-layout (wave-private)
#pragma unroll
    for (int nt = 0; nt < 4; ++nt) {
      Ps[wave][quad * 4 + 0][nt * 16 + lr] = to_bf16(sacc[nt][0]);
      Ps[wave][quad * 4 + 1][nt * 16 + lr] = to_bf16(sacc[nt][1]);
      Ps[wave][quad * 4 + 2][nt * 16 + lr] = to_bf16(sacc[nt][2]);
      Ps[wave][quad * 4 + 3][nt * 16 + lr] = to_bf16(sacc[nt][3]);
    }
#pragma unroll
    for (int ks = 0; ks < 2; ++ks) {
      int kq = ks * 32 + quad * 8;
      bf16x8 av = *(const bf16x8*)&Ps[wave][lr][kq];
#pragma unroll
      for (int nt = 0; nt < 4; ++nt) {
        bf16x8 bb = *(const bf16x8*)&Vs[cur][nt * 16 + lr][kq];
        oacc[nt] = __builtin_amdgcn_mfma_f32_16x16x32_bf16(av, bb, oacc[nt], 0, 0, 0);
      }
    }
    if (more) {  // stage prefetched tile into the other buffer
      *(uint4*)&Ks[cur ^ 1][r][c] = pk0; *(uint4*)&Ks[cur ^ 1][r][c + 8] = pk1;
      *(uint4*)&Vs[cur ^ 1][r][c] = pv0; *(uint4*)&Vs[cur ^ 1][r][c + 8] = pv1;
    }
  }
  if (a.nsplit == 1) {
    float inv[4];
#pragma unroll
    for (int rr = 0; rr < 4; ++rr) inv[rr] = 1.f / l_run[rr];
#pragma unroll
    for (int nt = 0; nt < 4; ++nt)
#pragma unroll
      for (int rr = 0; rr < 4; ++rr) {
        long row = b * 512 + qt * 64 + wave * 16 + quad * 4 + rr;
        float v = oacc[nt][rr] * inv[rr];
        if (a.obf16) ((u16*)a.O)[row * 512 + h * 64 + nt * 16 + lr] = to_bf16(v);
        else ((float*)a.O)[row * 512 + h * 64 + nt * 16 + lr] = v;
      }
  } else {
#pragma unroll
    for (int nt = 0; nt < 4; ++nt)
#pragma unroll
      for (int rr = 0; rr < 4; ++rr) {
        long row = b * 512 + qt * 64 + wave * 16 + quad * 4 + rr;
        a.Opart[((long)sp * 2048 + row) * 512 + h * 64 + nt * 16 + lr] = oacc[nt][rr];
      }
    if (lr == 0)
#pragma unroll
      for (int rr = 0; rr < 4; ++rr) {
        long row = b * 512 + qt * 64 + wave * 16 + quad * 4 + rr;
        long mi = (((long)sp * 2048 + row) * 8 + h) * 2;
        a.ml[mi] = m_run[rr]; a.ml[mi + 1] = l_run[rr];
      }
  }
}

// One-shot prep: embed, weight transposes, conv-w pack, pos cvt, ncm bias
// preset, SQP/loss zero-fill — descriptor-based block ranges, one launch.
struct PrepArgs { const void* a; const void* b; void* c; int mode, p0, p1, gx, gy; };
struct PrepBatch { PrepArgs p[10]; int end[10]; int np; };

__global__ __launch_bounds__(256) void prep_k(PrepBatch pb) {
  int bid = blockIdx.x, gi = 0;
  while (bid >= pb.end[gi]) ++gi;
  PrepArgs p = pb.p[gi];
  int lb = bid - (gi ? pb.end[gi - 1] : 0);
  int tid = threadIdx.x;
  __shared__ float t[32][33];
  if (p.mode == 0) {          // embed lookup
    int i = lb * 256 + tid;
    int row = i >> 9, d = i & 511;
    ((float*)p.c)[i] = ((const float*)p.a)[(long)((const int*)p.b)[row] * 512 + d];
  } else if (p.mode == 1) {   // fp32 [K][N] -> bf16 [N][K] transpose
    int K = p.p0, N = p.p1;
    int bx = lb % p.gx, by = (lb / p.gx) % p.gy, z = lb / (p.gx * p.gy);
    const float* in = (const float*)p.a + (long)z * K * N;
    u16* out = (u16*)p.c + (long)z * K * N;
    int n0 = bx * 32, k0 = by * 32;
    int tx = tid & 31, ty = tid >> 5;
    for (int j = 0; j < 32; j += 8) t[ty + j][tx] = in[(long)(k0 + ty + j) * N + n0 + tx];
    __syncthreads();
    for (int j = 0; j < 32; j += 8) out[(long)(n0 + ty + j) * K + k0 + tx] = to_bf16(t[tx][ty + j]);
  } else if (p.mode == 2) {   // conv weight pack
    int z = lb >> 12; int i = (lb & 4095) * 256 + tid;
    int o = i >> 11, k = i & 2047, r2 = k >> 9, d = k & 511;
    ((u16*)p.c)[(long)z * 1048576 + i] =
        to_bf16(((const float*)p.a)[(long)z * 1048576 + o * 2048 + d * 4 + r2]);
  } else if (p.mode == 3) {   // fp32 -> bf16 cvt
    int i = lb * 256 + tid;
    if (i < p.p0) ((u16*)p.c)[i] = to_bf16(((const float*)p.a)[i]);
  } else if (p.mode == 4) {   // ncm4 bias preset: c[i] = bias[layer*512 + (i&511)]
    int i = lb * 256 + tid;
    ((float*)p.c)[i] = ((const float*)p.a)[((i >> 18) << 9) + (i & 511)];
  } else {                    // mode 5: zero fill (uint4 units, p0 = count)
    int i = lb * 256 + tid;
    if (i < p.p0) { uint4 z4 = {0, 0, 0, 0}; ((uint4*)p.c)[i] = z4; }
  }
}

__global__ __launch_bounds__(256) void layernorm_k(const float* __restrict__ X,
                                                   const float* __restrict__ g,
                                                   const float* __restrict__ b,
                                                   u16* __restrict__ Y) {
  long row = blockIdx.x;
  const float* x = X + row * 512;
  int tid = threadIdx.x;
  float v0 = x[tid], v1 = x[tid + 256];
  __shared__ float red[256];
  red[tid] = v0 + v1; __syncthreads();
  for (int o = 128; o > 0; o >>= 1) { if (tid < o) red[tid] += red[tid + o]; __syncthreads(); }
  float mu = red[0] * (1.f / 512.f);
  __syncthreads();
  float d0 = v0 - mu, d1 = v1 - mu;
  red[tid] = d0 * d0 + d1 * d1; __syncthreads();
  for (int o = 128; o > 0; o >>= 1) { if (tid < o) red[tid] += red[tid + o]; __syncthreads(); }
  float rstd = rsqrtf(red[0] * (1.f / 512.f) + 1e-5f);
  Y[row * 512 + tid] = to_bf16(d0 * rstd * g[tid] + b[tid]);
  Y[row * 512 + tid + 256] = to_bf16(d1 * rstd * g[tid + 256] + b[tid + 256]);
}

__global__ __launch_bounds__(256) void finalize_k(const float* __restrict__ x,
                                                  const float* __restrict__ loss,
                                                  float* __restrict__ out) {
  long i = (long)blockIdx.x * 256 + threadIdx.x;
  if (i < 1048576) out[i] = x[i];
  else if (i == 1048576) out[i] = loss[0] * (1.f / (1048576.f * 4.f));
}

extern "C" void kernel_launch(void* const* d_in, const int* in_sizes, int n_in,
                              void* d_out, int out_size, void* d_ws, size_t ws_size,
                              hipStream_t stream) {
  (void)in_sizes; (void)n_in; (void)out_size;
  const int* trg = (const int*)d_in[0];
  const float* latent = (const float*)d_in[3];
  const float* mems = (const float*)d_in[4];
  const float* cmems = (const float*)d_in[5];
  const float* pos_emb = (const float*)d_in[6];
  const float* embed = (const float*)d_in[7];
  const float* W_self = (const float*)d_in[8];
  const float* ln1_g = (const float*)d_in[9];
  const float* ln1_b = (const float*)d_in[10];
  const float* conv_w = (const float*)d_in[11];
  const float* conv_b = (const float*)d_in[12];
  const float* W_src = (const float*)d_in[13];
  const float* ln2_g = (const float*)d_in[14];
  const float* ln2_b = (const float*)d_in[15];
  const float* w1 = (const float*)d_in[16];
  const float* b1 = (const float*)d_in[17];
  const float* w2 = (const float*)d_in[18];
  const float* b2 = (const float*)d_in[19];

  float* ws = (float*)d_ws;
  long off = 0;
  auto alloc = [&](long n) { float* p = ws + off; off += (n + 63) & ~63L; return p; };
  float* x    = alloc(1048576);
  float* t0   = alloc(1048576);
  float* t1   = alloc(1048576);
  float* ocm  = alloc(1048576);
  float* Opart= alloc(3145728);       // 3 splits (self-attn nsplit=3)
  float* mlb  = alloc(98304);         // [3][2048][8][2]
  float* Opart2 = alloc(2097152);     // cross partials; h1 aliases (disjoint liveness)
  u16* h1   = (u16*)Opart2;           // [2048][2048] bf16, written AFTER crossout reads Opart2
  float* mlb2 = alloc(65536);
  u16* qb   = (u16*)alloc(524288);
  u16* qc   = (u16*)alloc(524288);
  u16* xa   = (u16*)alloc(524288);
  u16* t1h  = (u16*)alloc(524288);
  u16* kbuf = (u16*)alloc(1179648);   // [4b][1152][512]: [cmem|mem|x] segments
  u16* vbuf = (u16*)alloc(1179648);   // [4b][512 d][1152 kv] transposed
  u16* kcm4 = (u16*)alloc(524288);    // all 4 layers
  u16* vcm4 = (u16*)alloc(524288);
  u16* klat4= (u16*)alloc(1048576);   // [4l][1024][512]
  u16* vlat4= (u16*)alloc(1048576);   // [4l][512][1024] transposed
  float* ncm4 = alloc(1048576);       // [4l][512][512]
  u16* SQP  = (u16*)alloc(9437184);   // [4][8][512][1152] bf16 pre-shifted, *8 folded
  u16* wts  = (u16*)alloc(2097152);
  u16* wsr  = (u16*)alloc(2097152);
  u16* w1t  = (u16*)alloc(2097152);
  u16* w2t  = (u16*)alloc(2097152);
  u16* cwt  = (u16*)alloc(2097152);
  u16* post = (u16*)alloc(294912);
  float* lossacc = alloc(64);
  if ((size_t)off * 4 > ws_size) return;

  // ===== one-shot prep launch =====
  PrepBatch PB; PB.np = 0; int ptot = 0;
  auto padd = [&](int mode, const void* a, const void* b, void* c,
                  int p0, int p1, int gx, int gy, int blocks) {
    PrepArgs pa; pa.a = a; pa.b = b; pa.c = c; pa.mode = mode;
    pa.p0 = p0; pa.p1 = p1; pa.gx = gx; pa.gy = gy;
    PB.p[PB.np] = pa; ptot += blocks; PB.end[PB.np] = ptot; PB.np++;
  };
  padd(0, embed, trg, x, 0, 0, 0, 0, 4096);
  padd(1, W_self, nullptr, wts, 512, 512, 16, 16, 4096);
  padd(1, W_src, nullptr, wsr, 512, 512, 16, 16, 4096);
  padd(1, w1, nullptr, w1t, 512, 2048, 64, 16, 4096);
  padd(1, w2, nullptr, w2t, 2048, 512, 16, 64, 4096);
  padd(2, conv_w, nullptr, cwt, 0, 0, 0, 0, 16384);
  padd(3, pos_emb, nullptr, post, 589824, 0, 0, 0, 2304);
  padd(4, conv_b, nullptr, ncm4, 0, 0, 0, 0, 4096);
  padd(5, nullptr, nullptr, SQP, 2359296, 0, 0, 0, 9216);
  padd(5, nullptr, nullptr, lossacc, 1, 0, 0, 0, 1);
  prep_k<<<dim3(ptot), 256, 0, stream>>>(PB);

  auto ga = []() { GemmArgs g; g.alpha = 1.f; g.bias = nullptr; g.res = nullptr; g.ldres = 512;
                   g.aml = nullptr;
                   g.amode = 0; g.cmode = 0; g.act = 0; g.smode = 0; g.bdiv = 1; g.kparts = 1;
                   g.sA1 = g.sA2 = g.sB1 = g.sB2 = g.sC1 = g.sC2 = 0; g.N = 0;
                   g.gx = g.gy = 1; return g; };
  GemmBatch GB; GB.ng = 0; int gtot = 0;
  auto badd = [&](GemmArgs g, int gx, int gy, int gz) {
    g.gx = gx; g.gy = gy;
    GB.g[GB.ng] = g; gtot += gx * gy * gz; GB.end[GB.ng] = gtot; GB.ng++;
  };
  auto brun = [&]() {
    gemmb_k<<<dim3(gtot), 256, 0, stream>>>(GB);
    GB.ng = 0; gtot = 0;
  };
  auto run1 = [&](GemmArgs g, int gx, int gy, int gz) { badd(g, gx, gy, gz); brun(); };

  FBatch FB; FB.nf = 0; int ztot = 0;
  auto fadd = [&](const u16* Q, const u16* K, const u16* V, const u16* QP, void* O,
                  int L, int nsplit, long sKb, long sVb, int ldV, int obf16,
                  float* Op, float* ml) {
    FAttnArgs a; a.Q = Q; a.K = K; a.V = V; a.QP = QP; a.O = O;
    a.Opart = Op; a.ml = ml;
    a.L = L; a.nsplit = nsplit; a.sKb = sKb; a.sVb = sVb; a.ldV = ldV;
    a.scale = 0.125f; a.obf16 = obf16;
    FB.a[FB.nf] = a; ztot += 4 * nsplit; FB.zend[FB.nf] = ztot; FB.nf++;
  };
  auto frun = [&]() {
    fattnb_k<<<dim3(8, 8, ztot), 256, 0, stream>>>(FB);
    FB.nf = 0; ztot = 0;
  };

  // ===== batchA: all-layer mem/latent work {klat4, vlat4, conv->ncm4} =====
  { GemmArgs g = ga(); g.A = latent; g.lda = 512; g.B = wsr + 262144; g.ldb = 512;
    g.sB1 = 1048576; g.C = klat4; g.ldc = 512; g.sC1 = 524288; g.cmode = 1; g.Kc = 512;
    badd(g, 8, 16, 4); }
  { GemmArgs g = ga(); g.A = latent; g.lda = 512; g.B = wsr + 2 * 262144; g.ldb = 512;
    g.sB1 = 1048576; g.C = vlat4; g.ldc = 1024; g.sC1 = 524288; g.cmode = 2; g.Kc = 512;
    badd(g, 8, 16, 4); }
  { GemmArgs g = ga(); g.A = mems; g.lda = 2048; g.sA1 = 1048576;
    g.B = cwt; g.ldb = 2048; g.sB1 = 1048576;
    g.C = ncm4; g.ldc = 512; g.sC1 = 262144; g.cmode = 3; g.kparts = 8; g.Kc = 256;
    badd(g, 8, 8, 32); }
  brun();

  for (int l = 0; l < 4; ++l) {
    const u16* Wt0 = wts + (l * 4 + 0) * 262144;
    const u16* Wt1 = wts + (l * 4 + 1) * 262144;
    const u16* Wt2 = wts + (l * 4 + 2) * 262144;
    const u16* Wt3 = wts + (l * 4 + 3) * 262144;
    const u16* Ws0 = wsr + (l * 4 + 0) * 262144;
    const u16* Ws3 = wsr + (l * 4 + 3) * 262144;
    const float* mem_l = mems + (long)l * 1048576;
    const float* cmem_l = cmems + (long)l * 262144;
    const u16* kcm_l = kcm4 + (long)l * 262144;
    const u16* vcm_l = vcm4 + (long)l * 262144;
    const u16* klat_l = klat4 + (long)l * 524288;
    const u16* vlat_l = vlat4 + (long)l * 524288;

    // ===== batchX: {qb, kbuf 3-seg, vbuf 3-seg} (+l0: kcm4, vcm4) =====
    { GemmArgs g = ga(); g.A = x; g.lda = 512; g.B = Wt0; g.ldb = 512; g.C = qb; g.ldc = 512;
      g.cmode = 1; g.Kc = 512; badd(g, 8, 32, 1); }
    { GemmArgs g = ga(); g.A = cmem_l; g.lda = 512; g.sA1 = 65536; g.B = Wt1; g.ldb = 512;
      g.C = kbuf; g.ldc = 512; g.sC1 = 589824; g.cmode = 1; g.Kc = 512; badd(g, 8, 2, 4); }
    { GemmArgs g = ga(); g.A = mem_l; g.lda = 512; g.sA1 = 262144; g.B = Wt1; g.ldb = 512;
      g.C = kbuf + 128 * 512; g.ldc = 512; g.sC1 = 589824; g.cmode = 1; g.Kc = 512;
      badd(g, 8, 8, 4); }
    { GemmArgs g = ga(); g.A = x; g.lda = 512; g.sA1 = 262144; g.B = Wt1; g.ldb = 512;
      g.C = kbuf + 640 * 512; g.ldc = 512; g.sC1 = 589824; g.cmode = 1; g.Kc = 512;
      badd(g, 8, 8, 4); }
    { GemmArgs g = ga(); g.A = cmem_l; g.lda = 512; g.sA1 = 65536; g.B = Wt2; g.ldb = 512;
      g.C = vbuf; g.ldc = 1152; g.sC1 = 589824; g.cmode = 2; g.Kc = 512; badd(g, 8, 2, 4); }
    { GemmArgs g = ga(); g.A = mem_l; g.lda = 512; g.sA1 = 262144; g.B = Wt2; g.ldb = 512;
      g.C = vbuf + 128; g.ldc = 1152; g.sC1 = 589824; g.cmode = 2; g.Kc = 512;
      badd(g, 8, 8, 4); }
    { GemmArgs g = ga(); g.A = x; g.lda = 512; g.sA1 = 262144; g.B = Wt2; g.ldb = 512;
      g.C = vbuf + 640; g.ldc = 1152; g.sC1 = 589824; g.cmode = 2; g.Kc = 512;
      badd(g, 8, 8, 4); }
    if (l == 0) {
      { GemmArgs g = ga(); g.A = ncm4; g.lda = 512; g.sA1 = 262144; g.B = wts + 262144;
        g.ldb = 512; g.sB1 = 1048576; g.C = kcm4; g.ldc = 512; g.sC1 = 262144;
        g.cmode = 1; g.Kc = 512; badd(g, 8, 8, 4); }
      { GemmArgs g = ga(); g.A = ncm4; g.lda = 512; g.sA1 = 262144; g.B = wts + 2 * 262144;
        g.ldb = 512; g.sB1 = 1048576; g.C = vcm4; g.ldc = 512; g.sC1 = 262144;
        g.cmode = 2; g.Kc = 512; badd(g, 8, 8, 4); }
    }
    brun();

    // ===== batchS: SQP shifted scatter (depends on qb) =====
    { GemmArgs g = ga(); g.A = qb; g.amode = 1; g.lda = 512; g.sA1 = 262144; g.sA2 = 64;
      g.B = post; g.ldb = 64; g.sB1 = 0; g.sB2 = 73728;
      g.C = SQP; g.ldc = 1152; g.sC1 = 4718592; g.sC2 = 589824;
      g.smode = 1; g.alpha = 8.f; g.bdiv = 8; g.Kc = 64; run1(g, 18, 8, 32); }

    // ===== self-attention (nsplit=3; combine fused into attnout GEMM) =====
    fadd(qb, kbuf, vbuf, SQP, nullptr, 1152, 3, 589824, 589824, 1152, 1, Opart, mlb);
    frun();
    { GemmArgs g = ga(); g.A = Opart; g.amode = 2; g.N = 3; g.aml = mlb; g.lda = 512;
      g.sA1 = 1048576; g.B = Wt3; g.ldb = 512; g.C = t1; g.ldc = 512; g.res = x; g.Kc = 512;
      run1(g, 8, 32, 1); }
    layernorm_k<<<2048, 256, 0, stream>>>(t1, ln1_g + l * 512, ln1_b + l * 512, xa);

    // batchQ: {rattn Q, cross Q} (both from xa)
    { GemmArgs g = ga(); g.A = xa; g.amode = 1; g.lda = 512; g.B = Wt0; g.ldb = 512;
      g.C = qb; g.ldc = 512; g.cmode = 1; g.Kc = 512; badd(g, 8, 32, 1); }
    { GemmArgs g = ga(); g.A = xa; g.amode = 1; g.lda = 512; g.B = Ws0; g.ldb = 512;
      g.C = qc; g.ldc = 512; g.cmode = 1; g.Kc = 512; badd(g, 8, 32, 1); }
    brun();

    // ===== rattn (compression loss) + cross attention, one batched launch =====
    fadd(qb, kcm_l, vcm_l, nullptr, ocm, 128, 1, 65536, 128, 512, 0, Opart, mlb);
    fadd(qb, kbuf + 128 * 512, vbuf + 128, nullptr, nullptr, 512, 2, 589824, 589824, 1152, 0,
         Opart, mlb);
    fadd(qc, klat_l, vlat_l, nullptr, nullptr, 256, 2, 131072, 256, 1024, 1, Opart2, mlb2);
    frun();

    { GemmArgs g = ga(); g.A = Opart2; g.amode = 2; g.N = 2; g.aml = mlb2; g.lda = 512;
      g.sA1 = 1048576; g.B = Ws3; g.ldb = 512; g.C = t0; g.ldc = 512; g.Kc = 512;
      run1(g, 8, 32, 1); }
    layernorm_k<<<2048, 256, 0, stream>>>(t0, ln2_g + l * 512, ln2_b + l * 512, t1h);

    // ===== FF1 + loss + preset-x in one launch =====
    { GemmArgs g = ga(); g.A = t1h; g.amode = 1; g.lda = 512; g.B = w1t + (long)l * 1048576;
      g.ldb = 512; g.C = h1; g.ldc = 2048; g.cmode = 1; g.bias = b1 + l * 2048; g.act = 1;
      g.Kc = 512; badd(g, 32, 32, 1); }
    { GemmArgs g = ga(); g.amode = 9; g.A = ocm; g.B = Opart; g.aml = mlb; g.C = lossacc;
      badd(g, 128, 1, 1); }
    { GemmArgs g = ga(); g.amode = 8; g.res = t0; g.bias = b2 + l * 512; g.C = x;
      badd(g, 1024, 1, 1); }
    brun();

    { GemmArgs g = ga(); g.A = h1; g.amode = 1; g.lda = 2048; g.B = w2t + (long)l * 1048576;
      g.ldb = 2048; g.C = x; g.ldc = 512; g.cmode = 3; g.kparts = 4; g.Kc = 512;
      run1(g, 8, 32, 4); }
  }
  finalize_k<<<4097, 256, 0, stream>>>(x, lossacc, (float*)d_out);
}

// Round 4
// 1116.317 us; speedup vs baseline: 1.3820x; 1.0155x over previous
//
#include <hip/hip_runtime.h>
#include <math.h>

typedef float floatx4 __attribute__((ext_vector_type(4)));
typedef __bf16 bf16x8 __attribute__((ext_vector_type(8)));
typedef unsigned short u16;

#define LDK 72  // LDS row stride in ushorts for fattn (144B, 16B-aligned)

__device__ inline u16 to_bf16(float f) {
  union { float f; unsigned u; } v; v.f = f;
  unsigned u = v.u;
  u += 0x7FFFu + ((u >> 16) & 1u);
  return (u16)(u >> 16);
}
__device__ inline float bf2f(u16 h) {
  union { unsigned u; float f; } v; v.u = ((unsigned)h) << 16; return v.f;
}

// async global->LDS, 16B per lane. LDS dest must be wave-uniform base
// (HW adds lane*16). Swizzled LDS content achieved by pre-swizzling the
// per-lane GLOBAL source address (rule #21: both-sides-or-neither).
__device__ inline void gload16(const void* g, void* l) {
  __builtin_amdgcn_global_load_lds(
      (const __attribute__((address_space(1))) unsigned int*)g,
      (__attribute__((address_space(3))) unsigned int*)l, 16, 0, 0);
}

struct GemmArgs {
  const void* A; const void* B; void* C; void* C2;
  int lda, ldb, ldc, N, Kc;   // N = nsplit for amode=2
  long sA1, sA2, sB1, sB2, sC1, sC2;
  float alpha;
  const float* bias; int biasz;   // bias index = col + zi*biasz
  const float* res; int ldres;
  const float* aml;  // amode=2/9: ml buffer [ns][2048][8][2]
  int amode;   // 0: A fp32, 1: A bf16, 2: A = flash-split combine, 9: loss
  int cmode;   // 0: fp32 C, 1: bf16 C, 2: bf16 C transposed, 3: fp32 atomicAdd,
               // 4: dual write fp32 C + bf16 C2
  int act;     // exact gelu
  int smode;   // shifted bf16 scatter: C[row][col+row-511] = bf16(v) if >=0
  int bdiv, kparts;
  int gx, gy;  // grid decomposition of this descriptor's block range
};

#define MAXG 10
struct GemmBatch {
  GemmArgs g[MAXG];
  int end[MAXG];   // cumulative block-count ends
  int ng;
};

// Grouped GEMM, 64x64 tile, K-step 64 + loss descriptor mode.
// XCD chunk swizzle: consecutive LOGICAL blocks (which share A panels) are
// given to the SAME XCD (hw round-robins %8) -> A fetched ~once/XCD.
__global__ __launch_bounds__(256) void gemmb_k(GemmBatch gb) {
  int nwg = gridDim.x;
  int hw = blockIdx.x;
  int qn = nwg >> 3, rn = nwg & 7;
  int xcd = hw & 7, ii = hw >> 3;
  int bid = (xcd < rn ? xcd * (qn + 1) : rn * (qn + 1) + (xcd - rn) * qn) + ii;

  int gi = 0;
  while (bid >= gb.end[gi]) ++gi;
  const GemmArgs g = gb.g[gi];
  int lb = bid - (gi ? gb.end[gi - 1] : 0);
  int tid = threadIdx.x;

  if (g.amode == 9) {  // MSE loss with fused 2-way flash combine
    const float* oc = (const float*)g.A;
    const float* Op = (const float*)g.B;
    const float* ml = g.aml;
    float s = 0.f;
    for (long i = (long)lb * 256 + tid; i < 1048576; i += 256L * g.gx) {
      int row = (int)(i >> 9), col = (int)(i & 511), h = col >> 6;
      const float* mlp = ml + ((long)row * 8 + h) * 2;
      float m0v = mlp[0], l0v = mlp[1];
      float m1v = mlp[32768], l1v = mlp[32769];
      float mm = fmaxf(m0v, m1v);
      float w0 = __expf(m0v - mm), w1 = __expf(m1v - mm);
      float ov = (w0 * Op[i] + w1 * Op[1048576 + i]) / (w0 * l0v + w1 * l1v);
      float d = oc[i] - ov; s += d * d;
    }
    for (int o = 32; o > 0; o >>= 1) s += __shfl_xor(s, o, 64);
    __shared__ float red[4];
    if ((tid & 63) == 0) red[tid >> 6] = s;
    __syncthreads();
    if (tid == 0) atomicAdd((float*)g.C, red[0] + red[1] + red[2] + red[3]);
    return;
  }

  int bx = lb % g.gx;
  int rem = lb / g.gx;
  int by = rem % g.gy;
  int z = rem / g.gy;

  int kp = z % g.kparts;
  int zz = z / g.kparts;
  int zi = zz / g.bdiv, zj = zz % g.bdiv;
  long aoff = (long)zi * g.sA1 + (long)zj * g.sA2;
  long boff = (long)zi * g.sB1 + (long)zj * g.sB2;
  long coff = (long)zi * g.sC1 + (long)zj * g.sC2;
  const float* Af = (const float*)g.A + aoff;
  const u16* Ah = (const u16*)g.A + aoff;
  const u16* Bh = (const u16*)g.B + boff;

  int m0 = by * 64, n0 = bx * 64;
  __shared__ u16 As[64][64];
  __shared__ u16 Bs[64][64];
  char* Asb = (char*)&As[0][0];
  char* Bsb = (char*)&Bs[0][0];
  int wave = tid >> 6, lane = tid & 63;
  int wr = (wave >> 1) * 32, wc = (wave & 1) * 32;
  int lr = lane & 15, qrow = lane >> 4;

  // async-staging geometry: lane covers LDS bytes o (linear); its global
  // source is the logical element whose swizzle lands at o.
  unsigned o0 = wave * 1024u + lane * 16u;
  unsigned o1 = o0 + 4096u;
  int ga_r0 = o0 >> 7, ga_r1 = o1 >> 7;
  int ga_c0 = (int)(o0 & 127u) ^ ((ga_r0 & 7) << 4);
  int ga_c1 = (int)(o1 & 127u) ^ ((ga_r1 & 7) << 4);
  long ldaB = (long)g.lda * 2, ldbB = (long)g.ldb * 2;
  // reg-staging geometry
  int r = tid >> 2, c16 = (tid & 3) << 4;
  int sw0 = (r << 7) + (((tid & 3) << 5) ^ ((r & 7) << 4));
  int sw1 = (r << 7) + ((((tid & 3) << 5) + 16) ^ ((r & 7) << 4));

  floatx4 acc[2][2];
#pragma unroll
  for (int i = 0; i < 2; ++i)
#pragma unroll
    for (int j = 0; j < 2; ++j)
#pragma unroll
      for (int rr = 0; rr < 4; ++rr) acc[i][j][rr] = 0.f;

  int kb0 = kp * g.Kc, kb1 = kb0 + g.Kc;
  for (int k0 = kb0; k0 < kb1; k0 += 64) {
    if (g.amode == 1) {
      const char* Ab = (const char*)Ah + ((long)m0 * g.lda + k0) * 2;
      gload16(Ab + ga_r0 * ldaB + ga_c0, Asb + wave * 1024);
      gload16(Ab + ga_r1 * ldaB + ga_c1, Asb + 4096 + wave * 1024);
    } else if (g.amode == 0) {
      const float* ap = Af + (long)(m0 + r) * g.lda + k0 + c16;
      float4 a0 = *(const float4*)ap, a1 = *(const float4*)(ap + 4);
      float4 a2 = *(const float4*)(ap + 8), a3 = *(const float4*)(ap + 12);
      union { u16 s[8]; uint4 v; } u0, u1;
      u0.s[0] = to_bf16(a0.x); u0.s[1] = to_bf16(a0.y); u0.s[2] = to_bf16(a0.z); u0.s[3] = to_bf16(a0.w);
      u0.s[4] = to_bf16(a1.x); u0.s[5] = to_bf16(a1.y); u0.s[6] = to_bf16(a1.z); u0.s[7] = to_bf16(a1.w);
      u1.s[0] = to_bf16(a2.x); u1.s[1] = to_bf16(a2.y); u1.s[2] = to_bf16(a2.z); u1.s[3] = to_bf16(a2.w);
      u1.s[4] = to_bf16(a3.x); u1.s[5] = to_bf16(a3.y); u1.s[6] = to_bf16(a3.z); u1.s[7] = to_bf16(a3.w);
      *(uint4*)(Asb + sw0) = u0.v; *(uint4*)(Asb + sw1) = u1.v;
    } else {  // amode 2: A = combine of g.N flash splits (ex-fcomb, fused)
      int row = m0 + r;
      int k = k0 + c16;               // all 16 cols in one head (k0%64==0)
      int ns = g.N;
      const float* mlp = g.aml + ((long)row * 8 + (k >> 6)) * 2;
      float mm = -1e30f;
#pragma unroll 3
      for (int s = 0; s < 3; ++s)
        if (s < ns) mm = fmaxf(mm, mlp[s * 32768]);
      float wgt[3]; float den = 0.f;
#pragma unroll 3
      for (int s = 0; s < 3; ++s)
        if (s < ns) { wgt[s] = __expf(mlp[s * 32768] - mm); den += wgt[s] * mlp[s * 32768 + 1]; }
      float inv = 1.f / den;
      float a16[16];
#pragma unroll
      for (int j = 0; j < 16; ++j) a16[j] = 0.f;
      const float* p0 = (const float*)g.A + (long)row * g.lda + k;
#pragma unroll 3
      for (int s = 0; s < 3; ++s)
        if (s < ns) {
          float w = wgt[s] * inv;
          const float* p = p0 + (long)s * g.sA1;
#pragma unroll
          for (int j = 0; j < 4; ++j) {
            float4 xx = *(const float4*)(p + j * 4);
            a16[j * 4 + 0] += w * xx.x; a16[j * 4 + 1] += w * xx.y;
            a16[j * 4 + 2] += w * xx.z; a16[j * 4 + 3] += w * xx.w;
          }
        }
      union { u16 s[8]; uint4 v; } u0, u1;
#pragma unroll
      for (int j = 0; j < 8; ++j) u0.s[j] = to_bf16(a16[j]);
#pragma unroll
      for (int j = 0; j < 8; ++j) u1.s[j] = to_bf16(a16[8 + j]);
      *(uint4*)(Asb + sw0) = u0.v; *(uint4*)(Asb + sw1) = u1.v;
    }
    {
      const char* Bb = (const char*)Bh + ((long)n0 * g.ldb + k0) * 2;
      gload16(Bb + ga_r0 * ldbB + ga_c0, Bsb + wave * 1024);
      gload16(Bb + ga_r1 * ldbB + ga_c1, Bsb + 4096 + wave * 1024);
    }
    __syncthreads();   // drains vmcnt (gload) + lgkm (ds_write)
#pragma unroll
    for (int ks = 0; ks < 2; ++ks) {
      int xk = ((ks * 32 + qrow * 8) << 1) ^ ((lr & 7) << 4);
      int rA0 = wr + lr, rB0 = wc + lr;
      bf16x8 a0 = *(const bf16x8*)(Asb + (rA0 << 7) + xk);
      bf16x8 a1 = *(const bf16x8*)(Asb + ((rA0 + 16) << 7) + xk);
      bf16x8 b0 = *(const bf16x8*)(Bsb + (rB0 << 7) + xk);
      bf16x8 b1 = *(const bf16x8*)(Bsb + ((rB0 + 16) << 7) + xk);
      acc[0][0] = __builtin_amdgcn_mfma_f32_16x16x32_bf16(a0, b0, acc[0][0], 0, 0, 0);
      acc[0][1] = __builtin_amdgcn_mfma_f32_16x16x32_bf16(a0, b1, acc[0][1], 0, 0, 0);
      acc[1][0] = __builtin_amdgcn_mfma_f32_16x16x32_bf16(a1, b0, acc[1][0], 0, 0, 0);
      acc[1][1] = __builtin_amdgcn_mfma_f32_16x16x32_bf16(a1, b1, acc[1][1], 0, 0, 0);
    }
    __syncthreads();
  }

#pragma unroll
  for (int mt = 0; mt < 2; ++mt)
#pragma unroll
    for (int nt = 0; nt < 2; ++nt) {
      int row0 = m0 + wr + mt * 16 + qrow * 4;
      int col = n0 + wc + nt * 16 + lr;
      if (g.cmode == 2) {
        ushort4 o;
        o.x = to_bf16(acc[mt][nt][0] * g.alpha);
        o.y = to_bf16(acc[mt][nt][1] * g.alpha);
        o.z = to_bf16(acc[mt][nt][2] * g.alpha);
        o.w = to_bf16(acc[mt][nt][3] * g.alpha);
        *(ushort4*)((u16*)g.C + coff + (long)col * g.ldc + row0) = o;
      } else {
#pragma unroll
        for (int rr = 0; rr < 4; ++rr) {
          int row = row0 + rr;
          float v = acc[mt][nt][rr] * g.alpha;
          if (g.cmode == 3) {
            atomicAdd((float*)g.C + coff + (long)row * g.ldc + col, v);
          } else if (g.smode) {
            int oc = col + row - 511;
            if (oc >= 0) ((u16*)g.C + coff)[(long)row * g.ldc + oc] = to_bf16(v);
          } else {
            if (g.bias) v += g.bias[col + zi * g.biasz];
            if (g.res) v += g.res[(long)row * g.ldres + col];
            if (g.act) v = 0.5f * v * (1.0f + erff(v * 0.70710678118654752f));
            if (g.cmode == 1) ((u16*)g.C + coff)[(long)row * g.ldc + col] = to_bf16(v);
            else if (g.cmode == 4) {
              ((float*)g.C + coff)[(long)row * g.ldc + col] = v;
              ((u16*)g.C2 + coff)[(long)row * g.ldc + col] = to_bf16(v);
            } else ((float*)g.C + coff)[(long)row * g.ldc + col] = v;
          }
        }
      }
    }
}

struct FAttnArgs {
  const u16* Q; const u16* K; const u16* V; const u16* QP;  // QP = pre-shifted SQP
  void* O; float* Opart; float* ml;
  int L, nsplit; long sKb, sVb; int ldV;
  float scale; int obf16;
};

struct FBatch {
  FAttnArgs a[3];
  int zend[3];  // cumulative z ends
  int nf;
};

// Fused flash attention, double-buffered K/V, optional pre-shifted pos bias,
// optional KV-split (unnormalized partials + m/l; combine fused in consumers).
__global__ __launch_bounds__(256) void fattnb_k(FBatch fb) {
  int zg = blockIdx.z;
  int fi = 0;
  while (zg >= fb.zend[fi]) ++fi;
  const FAttnArgs a = fb.a[fi];
  int zl = zg - (fi ? fb.zend[fi - 1] : 0);

  int qt = blockIdx.x, h = blockIdx.y;
  int b = zl / a.nsplit, sp = zl % a.nsplit;
  int Lc = a.L / a.nsplit, kt0 = sp * Lc, T = Lc >> 6;
  int tid = threadIdx.x, wave = tid >> 6, lane = tid & 63;
  int lr = lane & 15, quad = lane >> 4;
  __shared__ u16 Qs[64][LDK];
  __shared__ u16 Ks[2][64][LDK];
  __shared__ u16 Vs[2][64][LDK];
  __shared__ u16 Qp[4][16][LDK];
  __shared__ u16 Ps[4][16][LDK];
  int r = tid >> 2, c = (tid & 3) << 4;
  {
    const u16* qp = a.Q + (long)(b * 512 + qt * 64 + r) * 512 + h * 64 + c;
    *(uint4*)&Qs[r][c] = *(const uint4*)qp;
    *(uint4*)&Qs[r][c + 8] = *(const uint4*)(qp + 8);
  }
  const u16* Kb = a.K + (long)b * a.sKb + h * 64;
  const u16* Vb = a.V + (long)b * a.sVb + (long)(h * 64) * a.ldV;
  int qrow16 = lane >> 2, qc = (lane & 3) << 4;  // wave-private SQP tile loader
  const u16* QPr = a.QP ? a.QP + ((long)b * 8 + h) * 589824 +
                          (long)(qt * 64 + wave * 16 + qrow16) * 1152 : nullptr;
  // preload tile 0 straight into LDS buffer 0
  {
    const u16* kp = Kb + (long)(kt0 + r) * 512 + c;
    *(uint4*)&Ks[0][r][c] = *(const uint4*)kp;
    *(uint4*)&Ks[0][r][c + 8] = *(const uint4*)(kp + 8);
    const u16* vp = Vb + (long)r * a.ldV + kt0 + c;
    *(uint4*)&Vs[0][r][c] = *(const uint4*)vp;
    *(uint4*)&Vs[0][r][c + 8] = *(const uint4*)(vp + 8);
  }
  uint4 qpr0, qpr1;
  if (QPr) {  // 16 u16 per lane: two uint4s
    qpr0 = *(const uint4*)(QPr + kt0 + qc);
    qpr1 = *(const uint4*)(QPr + kt0 + qc + 8);
  }

  float m_run[4], l_run[4];
  floatx4 oacc[4];
#pragma unroll
  for (int i = 0; i < 4; ++i) {
    m_run[i] = -1e30f; l_run[i] = 0.f;
#pragma unroll
    for (int j = 0; j < 4; ++j) oacc[i][j] = 0.f;
  }

  for (int t = 0; t < T; ++t) {
    int cur = t & 1;
    bool more = (t + 1) < T;
    __syncthreads();
    uint4 pk0, pk1, pv0, pv1;
    if (more) {
      int kt = kt0 + (t + 1) * 64;
      const u16* kp = Kb + (long)(kt + r) * 512 + c;
      pk0 = *(const uint4*)kp; pk1 = *(const uint4*)(kp + 8);
      const u16* vp = Vb + (long)r * a.ldV + kt + c;
      pv0 = *(const uint4*)vp; pv1 = *(const uint4*)(vp + 8);
    }
    floatx4 sacc[4];
#pragma unroll
    for (int nt = 0; nt < 4; ++nt)
#pragma unroll
      for (int j = 0; j < 4; ++j) sacc[nt][j] = 0.f;
#pragma unroll
    for (int ks = 0; ks < 2; ++ks) {
      int kq = ks * 32 + quad * 8;
      bf16x8 av = *(const bf16x8*)&Qs[wave * 16 + lr][kq];
#pragma unroll
      for (int nt = 0; nt < 4; ++nt) {
        bf16x8 bb = *(const bf16x8*)&Ks[cur][nt * 16 + lr][kq];
        sacc[nt] = __builtin_amdgcn_mfma_f32_16x16x32_bf16(av, bb, sacc[nt], 0, 0, 0);
      }
    }
    if (QPr) {
      *(uint4*)&Qp[wave][qrow16][qc] = qpr0;
      *(uint4*)&Qp[wave][qrow16][qc + 8] = qpr1;
#pragma unroll
      for (int nt = 0; nt < 4; ++nt)
#pragma unroll
        for (int rr = 0; rr < 4; ++rr)
          sacc[nt][rr] = sacc[nt][rr] * a.scale + bf2f(Qp[wave][quad * 4 + rr][nt * 16 + lr]);
      if (more) {
        qpr0 = *(const uint4*)(QPr + kt0 + (t + 1) * 64 + qc);
        qpr1 = *(const uint4*)(QPr + kt0 + (t + 1) * 64 + qc + 8);
      }
    } else {
#pragma unroll
      for (int nt = 0; nt < 4; ++nt)
#pragma unroll
        for (int rr = 0; rr < 4; ++rr) sacc[nt][rr] *= a.scale;
    }
    // online softmax (rows replicated across the 16 lanes of a quad)
#pragma unroll
    for (int rr = 0; rr < 4; ++rr) {
      float m = -1e30f;
#pragma unroll
      for (int nt = 0; nt < 4; ++nt) m = fmaxf(m, sacc[nt][rr]);
      for (int o = 8; o > 0; o >>= 1) m = fmaxf(m, __shfl_xor(m, o, 64));
      float mn = fmaxf(m_run[rr], m);
      float al = __expf(m_run[rr] - mn);
      m_run[rr] = mn;
      float s = 0.f;
#pragma unroll
      for (int nt = 0; nt < 4; ++nt) {
        float p = __expf(sacc[nt][rr] - mn);
        sacc[nt][rr] = p;
        s += p;
      }
      for (int o = 8; o > 0; o >>= 1) s += __shfl_xor(s, o, 64);
      l_run[rr] = l_run[rr] * al + s;
#pragma unroll
      for (int nt = 0; nt < 4; ++nt) oacc[nt][rr] *= al;
    }
    // P (C-layout) -> LDS -> A-layout (wave-private)
#pragma unroll
    for (int nt = 0; nt < 4; ++nt) {
      Ps[wave][quad * 4 + 0][nt * 16 + lr] = to_bf16(sacc[nt][0]);
      Ps[wave][quad * 4 + 1][nt * 16 + lr] = to_bf16(sacc[nt][1]);
      Ps[wave][quad * 4 + 2][nt * 16 + lr] = to_bf16(sacc[nt][2]);
      Ps[wave][quad * 4 + 3][nt * 16 + lr] = to_bf16(sacc[nt][3]);
    }
#pragma unroll
    for (int ks = 0; ks < 2; ++ks) {
      int kq = ks * 32 + quad * 8;
      bf16x8 av = *(const bf16x8*)&Ps[wave][lr][kq];
#pragma unroll
      for (int nt = 0; nt < 4; ++nt) {
        bf16x8 bb = *(const bf16x8*)&Vs[cur][nt * 16 + lr][kq];
        oacc[nt] = __builtin_amdgcn_mfma_f32_16x16x32_bf16(av, bb, oacc[nt], 0, 0, 0);
      }
    }
    if (more) {  // stage prefetched tile into the other buffer
      *(uint4*)&Ks[cur ^ 1][r][c] = pk0; *(uint4*)&Ks[cur ^ 1][r][c + 8] = pk1;
      *(uint4*)&Vs[cur ^ 1][r][c] = pv0; *(uint4*)&Vs[cur ^ 1][r][c + 8] = pv1;
    }
  }
  if (a.nsplit == 1) {
    float inv[4];
#pragma unroll
    for (int rr = 0; rr < 4; ++rr) inv[rr] = 1.f / l_run[rr];
#pragma unroll
    for (int nt = 0; nt < 4; ++nt)
#pragma unroll
      for (int rr = 0; rr < 4; ++rr) {
        long row = b * 512 + qt * 64 + wave * 16 + quad * 4 + rr;
        float v = oacc[nt][rr] * inv[rr];
        if (a.obf16) ((u16*)a.O)[row * 512 + h * 64 + nt * 16 + lr] = to_bf16(v);
        else ((float*)a.O)[row * 512 + h * 64 + nt * 16 + lr] = v;
      }
  } else {
#pragma unroll
    for (int nt = 0; nt < 4; ++nt)
#pragma unroll
      for (int rr = 0; rr < 4; ++rr) {
        long row = b * 512 + qt * 64 + wave * 16 + quad * 4 + rr;
        a.Opart[((long)sp * 2048 + row) * 512 + h * 64 + nt * 16 + lr] = oacc[nt][rr];
      }
    if (lr == 0)
#pragma unroll
      for (int rr = 0; rr < 4; ++rr) {
        long row = b * 512 + qt * 64 + wave * 16 + quad * 4 + rr;
        long mi = (((long)sp * 2048 + row) * 8 + h) * 2;
        a.ml[mi] = m_run[rr]; a.ml[mi + 1] = l_run[rr];
      }
  }
}

// One-shot prep: embed (dual fp32+bf16), weight transposes, conv-w pack,
// pos cvt, fp32->bf16 activations, zero-fills — one launch.
struct PrepArgs { const void* a; const void* b; void* c; void* d; int mode, p0, p1, gx, gy; };
struct PrepBatch { PrepArgs p[12]; int end[12]; int np; };

__global__ __launch_bounds__(256) void prep_k(PrepBatch pb) {
  int bid = blockIdx.x, gi = 0;
  while (bid >= pb.end[gi]) ++gi;
  PrepArgs p = pb.p[gi];
  int lb = bid - (gi ? pb.end[gi - 1] : 0);
  int tid = threadIdx.x;
  __shared__ float t[32][33];
  if (p.mode == 0) {          // embed lookup, dual write fp32 + bf16
    int i = lb * 256 + tid;
    int row = i >> 9, d = i & 511;
    float v = ((const float*)p.a)[(long)((const int*)p.b)[row] * 512 + d];
    ((float*)p.c)[i] = v;
    ((u16*)p.d)[i] = to_bf16(v);
  } else if (p.mode == 1) {   // fp32 [K][N] -> bf16 [N][K] transpose
    int K = p.p0, N = p.p1;
    int bx = lb % p.gx, by = (lb / p.gx) % p.gy, z = lb / (p.gx * p.gy);
    const float* in = (const float*)p.a + (long)z * K * N;
    u16* out = (u16*)p.c + (long)z * K * N;
    int n0 = bx * 32, k0 = by * 32;
    int tx = tid & 31, ty = tid >> 5;
    for (int j = 0; j < 32; j += 8) t[ty + j][tx] = in[(long)(k0 + ty + j) * N + n0 + tx];
    __syncthreads();
    for (int j = 0; j < 32; j += 8) out[(long)(n0 + ty + j) * K + k0 + tx] = to_bf16(t[tx][ty + j]);
  } else if (p.mode == 2) {   // conv weight pack
    int z = lb >> 12; int i = (lb & 4095) * 256 + tid;
    int o = i >> 11, k = i & 2047, r2 = k >> 9, d = k & 511;
    ((u16*)p.c)[(long)z * 1048576 + i] =
        to_bf16(((const float*)p.a)[(long)z * 1048576 + o * 2048 + d * 4 + r2]);
  } else if (p.mode == 3) {   // fp32 -> bf16 cvt
    int i = lb * 256 + tid;
    if (i < p.p0) ((u16*)p.c)[i] = to_bf16(((const float*)p.a)[i]);
  } else {                    // mode 5: zero fill (uint4 units, p0 = count)
    int i = lb * 256 + tid;
    if (i < p.p0) { uint4 z4 = {0, 0, 0, 0}; ((uint4*)p.c)[i] = z4; }
  }
}

__global__ __launch_bounds__(256) void layernorm_k(const float* __restrict__ X,
                                                   const float* __restrict__ g,
                                                   const float* __restrict__ b,
                                                   u16* __restrict__ Y) {
  long row = blockIdx.x;
  const float* x = X + row * 512;
  int tid = threadIdx.x;
  float v0 = x[tid], v1 = x[tid + 256];
  __shared__ float red[256];
  red[tid] = v0 + v1; __syncthreads();
  for (int o = 128; o > 0; o >>= 1) { if (tid < o) red[tid] += red[tid + o]; __syncthreads(); }
  float mu = red[0] * (1.f / 512.f);
  __syncthreads();
  float d0 = v0 - mu, d1 = v1 - mu;
  red[tid] = d0 * d0 + d1 * d1; __syncthreads();
  for (int o = 128; o > 0; o >>= 1) { if (tid < o) red[tid] += red[tid + o]; __syncthreads(); }
  float rstd = rsqrtf(red[0] * (1.f / 512.f) + 1e-5f);
  Y[row * 512 + tid] = to_bf16(d0 * rstd * g[tid] + b[tid]);
  Y[row * 512 + tid + 256] = to_bf16(d1 * rstd * g[tid + 256] + b[tid + 256]);
}

__global__ __launch_bounds__(256) void finalize_k(const float* __restrict__ x,
                                                  const float* __restrict__ loss,
                                                  float* __restrict__ out) {
  long i = (long)blockIdx.x * 256 + threadIdx.x;
  if (i < 1048576) out[i] = x[i];
  else if (i == 1048576) out[i] = loss[0] * (1.f / (1048576.f * 4.f));
}

extern "C" void kernel_launch(void* const* d_in, const int* in_sizes, int n_in,
                              void* d_out, int out_size, void* d_ws, size_t ws_size,
                              hipStream_t stream) {
  (void)in_sizes; (void)n_in; (void)out_size;
  const int* trg = (const int*)d_in[0];
  const float* latent = (const float*)d_in[3];
  const float* mems = (const float*)d_in[4];
  const float* cmems = (const float*)d_in[5];
  const float* pos_emb = (const float*)d_in[6];
  const float* embed = (const float*)d_in[7];
  const float* W_self = (const float*)d_in[8];
  const float* ln1_g = (const float*)d_in[9];
  const float* ln1_b = (const float*)d_in[10];
  const float* conv_w = (const float*)d_in[11];
  const float* conv_b = (const float*)d_in[12];
  const float* W_src = (const float*)d_in[13];
  const float* ln2_g = (const float*)d_in[14];
  const float* ln2_b = (const float*)d_in[15];
  const float* w1 = (const float*)d_in[16];
  const float* b1 = (const float*)d_in[17];
  const float* w2 = (const float*)d_in[18];
  const float* b2 = (const float*)d_in[19];

  float* ws = (float*)d_ws;
  long off = 0;
  auto alloc = [&](long n) { float* p = ws + off; off += (n + 63) & ~63L; return p; };
  float* x    = alloc(1048576);
  float* t0   = alloc(1048576);
  float* t1   = alloc(1048576);
  float* ocm  = alloc(1048576);
  float* Opart= alloc(3145728);       // 3 splits (self-attn nsplit=3)
  float* mlb  = alloc(98304);         // [3][2048][8][2]
  float* Opart2 = alloc(2097152);     // cross partials; h1 aliases (disjoint liveness)
  u16* h1   = (u16*)Opart2;           // [2048][2048] bf16, written AFTER crossout reads Opart2
  float* mlb2 = alloc(65536);
  u16* qb   = (u16*)alloc(524288);
  u16* qc   = (u16*)alloc(524288);
  u16* xa   = (u16*)alloc(524288);
  u16* t1h  = (u16*)alloc(524288);
  u16* xh   = (u16*)alloc(262144);    // bf16 copy of layer input x
  u16* kbuf = (u16*)alloc(1179648);   // [4b][1152][512]: [cmem|mem|x] segments
  u16* vbuf = (u16*)alloc(1179648);   // [4b][512 d][1152 kv] transposed
  u16* kcm4 = (u16*)alloc(524288);    // all 4 layers
  u16* vcm4 = (u16*)alloc(524288);
  u16* klat4= (u16*)alloc(1048576);   // [4l][1024][512]
  u16* vlat4= (u16*)alloc(1048576);   // [4l][512][1024] transposed
  u16* ncm4h= (u16*)alloc(524288);    // [4l][512][512] bf16 (conv out, bias fused)
  u16* memh = (u16*)alloc(2097152);   // bf16 mems
  u16* cmemh= (u16*)alloc(524288);    // bf16 cmems
  u16* lath = (u16*)alloc(262144);    // bf16 latent
  u16* SQP  = (u16*)alloc(9437184);   // [4][8][512][1152] bf16 pre-shifted, *8 folded
  u16* wts  = (u16*)alloc(2097152);
  u16* wsr  = (u16*)alloc(2097152);
  u16* w1t  = (u16*)alloc(2097152);
  u16* w2t  = (u16*)alloc(2097152);
  u16* cwt  = (u16*)alloc(2097152);
  u16* post = (u16*)alloc(294912);
  float* lossacc = alloc(64);
  if ((size_t)off * 4 > ws_size) return;

  // ===== one-shot prep launch =====
  PrepBatch PB; PB.np = 0; int ptot = 0;
  auto padd = [&](int mode, const void* a, const void* b, void* c, void* d,
                  int p0, int p1, int gx, int gy, int blocks) {
    PrepArgs pa; pa.a = a; pa.b = b; pa.c = c; pa.d = d; pa.mode = mode;
    pa.p0 = p0; pa.p1 = p1; pa.gx = gx; pa.gy = gy;
    PB.p[PB.np] = pa; ptot += blocks; PB.end[PB.np] = ptot; PB.np++;
  };
  padd(0, embed, trg, x, xh, 0, 0, 0, 0, 4096);
  padd(1, W_self, nullptr, wts, nullptr, 512, 512, 16, 16, 4096);
  padd(1, W_src, nullptr, wsr, nullptr, 512, 512, 16, 16, 4096);
  padd(1, w1, nullptr, w1t, nullptr, 512, 2048, 64, 16, 4096);
  padd(1, w2, nullptr, w2t, nullptr, 2048, 512, 16, 64, 4096);
  padd(2, conv_w, nullptr, cwt, nullptr, 0, 0, 0, 0, 16384);
  padd(3, pos_emb, nullptr, post, nullptr, 589824, 0, 0, 0, 2304);
  padd(3, mems, nullptr, memh, nullptr, 4194304, 0, 0, 0, 16384);
  padd(3, cmems, nullptr, cmemh, nullptr, 1048576, 0, 0, 0, 4096);
  padd(3, latent, nullptr, lath, nullptr, 524288, 0, 0, 0, 2048);
  padd(5, nullptr, nullptr, SQP, nullptr, 2359296, 0, 0, 0, 9216);
  padd(5, nullptr, nullptr, lossacc, nullptr, 1, 0, 0, 0, 1);
  prep_k<<<dim3(ptot), 256, 0, stream>>>(PB);

  auto ga = []() { GemmArgs g; g.alpha = 1.f; g.bias = nullptr; g.biasz = 0; g.res = nullptr;
                   g.ldres = 512; g.aml = nullptr; g.C2 = nullptr;
                   g.amode = 0; g.cmode = 0; g.act = 0; g.smode = 0; g.bdiv = 1; g.kparts = 1;
                   g.sA1 = g.sA2 = g.sB1 = g.sB2 = g.sC1 = g.sC2 = 0; g.N = 0;
                   g.gx = g.gy = 1; return g; };
  GemmBatch GB; GB.ng = 0; int gtot = 0;
  auto badd = [&](GemmArgs g, int gx, int gy, int gz) {
    g.gx = gx; g.gy = gy;
    GB.g[GB.ng] = g; gtot += gx * gy * gz; GB.end[GB.ng] = gtot; GB.ng++;
  };
  auto brun = [&]() {
    gemmb_k<<<dim3(gtot), 256, 0, stream>>>(GB);
    GB.ng = 0; gtot = 0;
  };
  auto run1 = [&](GemmArgs g, int gx, int gy, int gz) { badd(g, gx, gy, gz); brun(); };

  FBatch FB; FB.nf = 0; int ztot = 0;
  auto fadd = [&](const u16* Q, const u16* K, const u16* V, const u16* QP, void* O,
                  int L, int nsplit, long sKb, long sVb, int ldV, int obf16,
                  float* Op, float* ml) {
    FAttnArgs a; a.Q = Q; a.K = K; a.V = V; a.QP = QP; a.O = O;
    a.Opart = Op; a.ml = ml;
    a.L = L; a.nsplit = nsplit; a.sKb = sKb; a.sVb = sVb; a.ldV = ldV;
    a.scale = 0.125f; a.obf16 = obf16;
    FB.a[FB.nf] = a; ztot += 4 * nsplit; FB.zend[FB.nf] = ztot; FB.nf++;
  };
  auto frun = [&]() {
    fattnb_k<<<dim3(8, 8, ztot), 256, 0, stream>>>(FB);
    FB.nf = 0; ztot = 0;
  };

  // ===== batchA: all-layer mem/latent work {klat4, vlat4, conv->ncm4h} =====
  { GemmArgs g = ga(); g.A = lath; g.amode = 1; g.lda = 512; g.B = wsr + 262144; g.ldb = 512;
    g.sB1 = 1048576; g.C = klat4; g.ldc = 512; g.sC1 = 524288; g.cmode = 1; g.Kc = 512;
    badd(g, 8, 16, 4); }
  { GemmArgs g = ga(); g.A = lath; g.amode = 1; g.lda = 512; g.B = wsr + 2 * 262144; g.ldb = 512;
    g.sB1 = 1048576; g.C = vlat4; g.ldc = 1024; g.sC1 = 524288; g.cmode = 2; g.Kc = 512;
    badd(g, 8, 16, 4); }
  { GemmArgs g = ga(); g.A = memh; g.amode = 1; g.lda = 2048; g.sA1 = 1048576;
    g.B = cwt; g.ldb = 2048; g.sB1 = 1048576;
    g.C = ncm4h; g.ldc = 512; g.sC1 = 262144; g.cmode = 1;
    g.bias = conv_b; g.biasz = 512; g.Kc = 2048;
    badd(g, 8, 8, 4); }
  brun();

  for (int l = 0; l < 4; ++l) {
    const u16* Wt0 = wts + (l * 4 + 0) * 262144;
    const u16* Wt1 = wts + (l * 4 + 1) * 262144;
    const u16* Wt2 = wts + (l * 4 + 2) * 262144;
    const u16* Wt3 = wts + (l * 4 + 3) * 262144;
    const u16* Ws0 = wsr + (l * 4 + 0) * 262144;
    const u16* Ws3 = wsr + (l * 4 + 3) * 262144;
    const u16* memh_l = memh + (long)l * 1048576;
    const u16* cmemh_l = cmemh + (long)l * 262144;
    const u16* kcm_l = kcm4 + (long)l * 262144;
    const u16* vcm_l = vcm4 + (long)l * 262144;
    const u16* klat_l = klat4 + (long)l * 524288;
    const u16* vlat_l = vlat4 + (long)l * 524288;

    // ===== batchX: {qb, kbuf 3-seg, vbuf 3-seg} (+l0: kcm4, vcm4) =====
    { GemmArgs g = ga(); g.A = xh; g.amode = 1; g.lda = 512; g.B = Wt0; g.ldb = 512;
      g.C = qb; g.ldc = 512; g.cmode = 1; g.Kc = 512; badd(g, 8, 32, 1); }
    { GemmArgs g = ga(); g.A = cmemh_l; g.amode = 1; g.lda = 512; g.sA1 = 65536;
      g.B = Wt1; g.ldb = 512;
      g.C = kbuf; g.ldc = 512; g.sC1 = 589824; g.cmode = 1; g.Kc = 512; badd(g, 8, 2, 4); }
    { GemmArgs g = ga(); g.A = memh_l; g.amode = 1; g.lda = 512; g.sA1 = 262144;
      g.B = Wt1; g.ldb = 512;
      g.C = kbuf + 128 * 512; g.ldc = 512; g.sC1 = 589824; g.cmode = 1; g.Kc = 512;
      badd(g, 8, 8, 4); }
    { GemmArgs g = ga(); g.A = xh; g.amode = 1; g.lda = 512; g.sA1 = 262144;
      g.B = Wt1; g.ldb = 512;
      g.C = kbuf + 640 * 512; g.ldc = 512; g.sC1 = 589824; g.cmode = 1; g.Kc = 512;
      badd(g, 8, 8, 4); }
    { GemmArgs g = ga(); g.A = cmemh_l; g.amode = 1; g.lda = 512; g.sA1 = 65536;
      g.B = Wt2; g.ldb = 512;
      g.C = vbuf; g.ldc = 1152; g.sC1 = 589824; g.cmode = 2; g.Kc = 512; badd(g, 8, 2, 4); }
    { GemmArgs g = ga(); g.A = memh_l; g.amode = 1; g.lda = 512; g.sA1 = 262144;
      g.B = Wt2; g.ldb = 512;
      g.C = vbuf + 128; g.ldc = 1152; g.sC1 = 589824; g.cmode = 2; g.Kc = 512;
      badd(g, 8, 8, 4); }
    { GemmArgs g = ga(); g.A = xh; g.amode = 1; g.lda = 512; g.sA1 = 262144;
      g.B = Wt2; g.ldb = 512;
      g.C = vbuf + 640; g.ldc = 1152; g.sC1 = 589824; g.cmode = 2; g.Kc = 512;
      badd(g, 8, 8, 4); }
    if (l == 0) {
      { GemmArgs g = ga(); g.A = ncm4h; g.amode = 1; g.lda = 512; g.sA1 = 262144;
        g.B = wts + 262144; g.ldb = 512; g.sB1 = 1048576;
        g.C = kcm4; g.ldc = 512; g.sC1 = 262144; g.cmode = 1; g.Kc = 512; badd(g, 8, 8, 4); }
      { GemmArgs g = ga(); g.A = ncm4h; g.amode = 1; g.lda = 512; g.sA1 = 262144;
        g.B = wts + 2 * 262144; g.ldb = 512; g.sB1 = 1048576;
        g.C = vcm4; g.ldc = 512; g.sC1 = 262144; g.cmode = 2; g.Kc = 512; badd(g, 8, 8, 4); }
    }
    brun();

    // ===== batchS: SQP shifted scatter (depends on qb) =====
    { GemmArgs g = ga(); g.A = qb; g.amode = 1; g.lda = 512; g.sA1 = 262144; g.sA2 = 64;
      g.B = post; g.ldb = 64; g.sB1 = 0; g.sB2 = 73728;
      g.C = SQP; g.ldc = 1152; g.sC1 = 4718592; g.sC2 = 589824;
      g.smode = 1; g.alpha = 8.f; g.bdiv = 8; g.Kc = 64; run1(g, 18, 8, 32); }

    // ===== self-attention (nsplit=3; combine fused into attnout GEMM) =====
    fadd(qb, kbuf, vbuf, SQP, nullptr, 1152, 3, 589824, 589824, 1152, 1, Opart, mlb);
    frun();
    { GemmArgs g = ga(); g.A = Opart; g.amode = 2; g.N = 3; g.aml = mlb; g.lda = 512;
      g.sA1 = 1048576; g.B = Wt3; g.ldb = 512; g.C = t1; g.ldc = 512; g.res = x; g.Kc = 512;
      run1(g, 8, 32, 1); }
    layernorm_k<<<2048, 256, 0, stream>>>(t1, ln1_g + l * 512, ln1_b + l * 512, xa);

    // batchQ: {rattn Q, cross Q} (both from xa)
    { GemmArgs g = ga(); g.A = xa; g.amode = 1; g.lda = 512; g.B = Wt0; g.ldb = 512;
      g.C = qb; g.ldc = 512; g.cmode = 1; g.Kc = 512; badd(g, 8, 32, 1); }
    { GemmArgs g = ga(); g.A = xa; g.amode = 1; g.lda = 512; g.B = Ws0; g.ldb = 512;
      g.C = qc; g.ldc = 512; g.cmode = 1; g.Kc = 512; badd(g, 8, 32, 1); }
    brun();

    // ===== rattn (compression loss) + cross attention, one batched launch =====
    fadd(qb, kcm_l, vcm_l, nullptr, ocm, 128, 1, 65536, 128, 512, 0, Opart, mlb);
    fadd(qb, kbuf + 128 * 512, vbuf + 128, nullptr, nullptr, 512, 2, 589824, 589824, 1152, 0,
         Opart, mlb);
    fadd(qc, klat_l, vlat_l, nullptr, nullptr, 256, 2, 131072, 256, 1024, 1, Opart2, mlb2);
    frun();

    { GemmArgs g = ga(); g.A = Opart2; g.amode = 2; g.N = 2; g.aml = mlb2; g.lda = 512;
      g.sA1 = 1048576; g.B = Ws3; g.ldb = 512; g.C = t0; g.ldc = 512; g.Kc = 512;
      run1(g, 8, 32, 1); }
    layernorm_k<<<2048, 256, 0, stream>>>(t0, ln2_g + l * 512, ln2_b + l * 512, t1h);

    // ===== FF1 + loss in one launch =====
    { GemmArgs g = ga(); g.A = t1h; g.amode = 1; g.lda = 512; g.B = w1t + (long)l * 1048576;
      g.ldb = 512; g.C = h1; g.ldc = 2048; g.cmode = 1; g.bias = b1 + l * 2048; g.act = 1;
      g.Kc = 512; badd(g, 32, 32, 1); }
    { GemmArgs g = ga(); g.amode = 9; g.A = ocm; g.B = Opart; g.aml = mlb; g.C = lossacc;
      badd(g, 128, 1, 1); }
    brun();

    // ===== FF2: x = h1*w2 + b2 + t0, dual write fp32 x + bf16 xh =====
    { GemmArgs g = ga(); g.A = h1; g.amode = 1; g.lda = 2048;
      g.B = w2t + (long)l * 1048576; g.ldb = 2048;
      g.C = x; g.C2 = xh; g.ldc = 512; g.cmode = 4;
      g.bias = b2 + l * 512; g.res = t0; g.Kc = 2048;
      run1(g, 8, 32, 1); }
  }
  finalize_k<<<4097, 256, 0, stream>>>(x, lossacc, (float*)d_out);
}